// Round 2
// baseline (1188.473 us; speedup 1.0000x reference)
//
#include <hip/hip_runtime.h>

typedef __attribute__((ext_vector_type(8))) short bf16x8;
typedef __attribute__((ext_vector_type(4))) float f32x4;
typedef unsigned short ushort_t;
typedef unsigned int uint32;

#define DEV __device__ __forceinline__

// round-to-nearest-even f32 -> bf16 (bits)
DEV ushort_t f2bf(float f) {
    uint32 u = __float_as_uint(f);
    uint32 r = (u + 0x7FFFu + ((u >> 16) & 1u)) >> 16;
    return (ushort_t)r;
}

#define MFMA16(a, b, c) __builtin_amdgcn_mfma_f32_16x16x32_bf16((a), (b), (c), 0, 0, 0)

DEV void gload_lds16(const void* g, void* l) {
    __builtin_amdgcn_global_load_lds((const __attribute__((address_space(1))) void*)g,
                                     (__attribute__((address_space(3))) void*)l,
                                     16, 0, 0);
}

// ---------------------------------------------------------------------------
// init: copy f32 x -> d_out (running x buffer) and bf16 xb
// ---------------------------------------------------------------------------
__global__ __launch_bounds__(256) void init_x(const float* __restrict__ xin,
                                              float* __restrict__ x,
                                              ushort_t* __restrict__ xb, int n4) {
    int i = blockIdx.x * 256 + threadIdx.x;
    if (i >= n4) return;
    float4 v = ((const float4*)xin)[i];
    ((float4*)x)[i] = v;
    ushort4 h;
    h.x = f2bf(v.x); h.y = f2bf(v.y); h.z = f2bf(v.z); h.w = f2bf(v.w);
    ((ushort4*)xb)[i] = h;
}

// ---------------------------------------------------------------------------
// transpose + convert: src (K x N f32, row-major) -> dst (N x K bf16)
// ---------------------------------------------------------------------------
__global__ __launch_bounds__(256) void transpose_convert(const float* __restrict__ src,
                                                         ushort_t* __restrict__ dst,
                                                         int K, int N) {
    __shared__ float tile[32][33];
    int tx = threadIdx.x, ty = threadIdx.y;  // (32,8)
    int nt = blockIdx.x * 32, kt = blockIdx.y * 32;
#pragma unroll
    for (int j = 0; j < 4; ++j)
        tile[ty + j * 8][tx] = src[(size_t)(kt + ty + j * 8) * N + nt + tx];
    __syncthreads();
#pragma unroll
    for (int j = 0; j < 4; ++j)
        dst[(size_t)(nt + ty + j * 8) * K + kt + tx] = f2bf(tile[tx][ty + j * 8]);
}

// ---------------------------------------------------------------------------
// GEMM: C[M,N] = A[M,K] @ BT[N,K]^T + bias (bf16 in, f32 acc)
// 128x128 tile, BK=32, 4 waves (2x2), each wave 64x64 = 4x4 16x16 frags.
// MODE: 0 = f32 out, 1 = bf16 out, 2 = fused QKV split (q,k row-major bf16;
//       v written transposed per-head into vt (B,H,DH,S)).
// 1D grid with XCD-aware bijective swizzle (m204).
// ---------------------------------------------------------------------------
template <int MODE, int RELU>
__global__ __launch_bounds__(256) void gemm_bt(const ushort_t* __restrict__ A,
                                               const ushort_t* __restrict__ BT,
                                               const float* __restrict__ bias,
                                               void* __restrict__ Cout,
                                               int M, int N, int K, int gx,
                                               ushort_t* __restrict__ qout,
                                               ushort_t* __restrict__ kout,
                                               ushort_t* __restrict__ vtout,
                                               const float* __restrict__ bq,
                                               const float* __restrict__ bk,
                                               const float* __restrict__ bv) {
    __shared__ ushort_t a_lds[128 * 32];
    __shared__ ushort_t b_lds[128 * 32];
    // XCD-aware bijective swizzle: contiguous chunks per XCD
    const int nwg = gridDim.x;
    const int q8 = nwg >> 3, r8 = nwg & 7;
    const int xcd = blockIdx.x & 7, idx = blockIdx.x >> 3;
    const int swz = (xcd < r8 ? xcd * (q8 + 1) : r8 * (q8 + 1) + (xcd - r8) * q8) + idx;
    const int bxi = swz % gx, byi = swz / gx;

    const int tid = threadIdx.x;
    const int w = tid >> 6, lane = tid & 63;
    const int wm = w >> 1, wn = w & 1;
    const int lr = lane & 15, lh = lane >> 4;
    const int row0 = byi * 128, col0 = bxi * 128;

    f32x4 acc[4][4] = {};

    const int e0 = tid * 8;          // LDS elem offset, chunk 0 (16B per lane)
    const int r0 = e0 >> 5, c0 = e0 & 31;
    const int e1 = e0 + 2048;        // chunk 1
    const int r1 = r0 + 64;

    const ushort_t* Ab = A + (size_t)row0 * K;
    const ushort_t* Bb = BT + (size_t)col0 * K;

    for (int k0 = 0; k0 < K; k0 += 32) {
        __syncthreads();
        gload_lds16(Ab + (size_t)r0 * K + k0 + c0, &a_lds[e0]);
        gload_lds16(Ab + (size_t)r1 * K + k0 + c0, &a_lds[e1]);
        gload_lds16(Bb + (size_t)r0 * K + k0 + c0, &b_lds[e0]);
        gload_lds16(Bb + (size_t)r1 * K + k0 + c0, &b_lds[e1]);
        __syncthreads();  // drains vmcnt (global_load_lds) + barrier

        bf16x8 af[4], bfr[4];
#pragma unroll
        for (int mi = 0; mi < 4; ++mi)
            af[mi] = *(const bf16x8*)&a_lds[(wm * 64 + mi * 16 + lr) * 32 + lh * 8];
#pragma unroll
        for (int ni = 0; ni < 4; ++ni)
            bfr[ni] = *(const bf16x8*)&b_lds[(wn * 64 + ni * 16 + lr) * 32 + lh * 8];
#pragma unroll
        for (int mi = 0; mi < 4; ++mi)
#pragma unroll
            for (int ni = 0; ni < 4; ++ni)
                acc[mi][ni] = MFMA16(af[mi], bfr[ni], acc[mi][ni]);
    }

#pragma unroll
    for (int mi = 0; mi < 4; ++mi) {
#pragma unroll
        for (int ni = 0; ni < 4; ++ni) {
            const int col = col0 + wn * 64 + ni * 16 + lr;
            const int rowb = row0 + wm * 64 + mi * 16 + lh * 4;
            if (MODE == 2) {
                if (col < 2048) {
                    const float bvv = (col < 1024) ? bq[col] : bk[col - 1024];
                    ushort_t* dst = (col < 1024) ? qout : kout;
                    const int c = col & 1023;
#pragma unroll
                    for (int r = 0; r < 4; ++r)
                        dst[(size_t)(rowb + r) * 1024 + c] = f2bf(acc[mi][ni][r] + bvv);
                } else {
                    const int d = col - 2048;
                    const int h = d >> 6, dd = d & 63;
                    const int b = rowb >> 10, s = rowb & 1023;
                    const float bvv = bv[d];
                    ushort4 h4;
                    h4.x = f2bf(acc[mi][ni][0] + bvv);
                    h4.y = f2bf(acc[mi][ni][1] + bvv);
                    h4.z = f2bf(acc[mi][ni][2] + bvv);
                    h4.w = f2bf(acc[mi][ni][3] + bvv);
                    *(ushort4*)&vtout[(((size_t)(b * 16 + h) * 64 + dd) << 10) + s] = h4;
                }
            } else {
                const float bvv = bias[col];
#pragma unroll
                for (int r = 0; r < 4; ++r) {
                    float val = acc[mi][ni][r] + bvv;
                    if (RELU) val = fmaxf(val, 0.f);
                    if (MODE == 1)
                        ((ushort_t*)Cout)[(size_t)(rowb + r) * N + col] = f2bf(val);
                    else
                        ((float*)Cout)[(size_t)(rowb + r) * N + col] = val;
                }
            }
        }
    }
}

// ---------------------------------------------------------------------------
// fused causal flash attention: one block per (b,h,64-row q tile), 4
// independent waves (no barriers), wave = 16 q rows, key tiles of 32.
// q/k: (B*S, 1024) bf16 row-major; vt: (B,H,64,S) bf16; o: (B*S,1024) bf16.
// K and Vt read directly from global (L2-resident per head).
// ---------------------------------------------------------------------------
__global__ __launch_bounds__(256) void attn_kernel(const ushort_t* __restrict__ q,
                                                   const ushort_t* __restrict__ k,
                                                   const ushort_t* __restrict__ vt,
                                                   ushort_t* __restrict__ o) {
    __shared__ ushort_t p_lds[4][16 * 32];

    const int bh = blockIdx.y;
    const int b = bh >> 4, h = bh & 15;
    const int qt = blockIdx.x;
    const int tid = threadIdx.x, w = tid >> 6, lane = tid & 63;
    const int lr = lane & 15, lh = lane >> 4;
    const int qbase = qt * 64 + w * 16;
    const size_t headoff = (size_t)b * 1024 * 1024 + h * 64;
    const size_t vhead = (size_t)(b * 16 + h) << 16;  // *64*1024

    bf16x8 qf[2];
#pragma unroll
    for (int ks = 0; ks < 2; ++ks)
        qf[ks] = *(const bf16x8*)&q[headoff + (size_t)(qbase + lr) * 1024 + ks * 32 + lh * 8];

    f32x4 oacc[4] = {};
    float m[4] = {-INFINITY, -INFINITY, -INFINITY, -INFINITY};
    float ls[4] = {0.f, 0.f, 0.f, 0.f};

    const int jmax = qbase + 15;  // per-wave causal bound
    for (int j0 = 0; j0 <= jmax; j0 += 32) {
        f32x4 s0 = {}, s1 = {};
#pragma unroll
        for (int ks = 0; ks < 2; ++ks) {
            bf16x8 k0f = *(const bf16x8*)&k[headoff + (size_t)(j0 + lr) * 1024 + ks * 32 + lh * 8];
            s0 = MFMA16(qf[ks], k0f, s0);
            bf16x8 k1f = *(const bf16x8*)&k[headoff + (size_t)(j0 + 16 + lr) * 1024 + ks * 32 + lh * 8];
            s1 = MFMA16(qf[ks], k1f, s1);
        }
        const float scale = 0.125f;
#pragma unroll
        for (int r = 0; r < 4; ++r) {
            const int row = qbase + lh * 4 + r;
            s0[r] = ((j0 + lr) <= row) ? s0[r] * scale : -1e9f;
            s1[r] = ((j0 + 16 + lr) <= row) ? s1[r] * scale : -1e9f;
        }
        // online softmax (rows live in 16-lane groups)
#pragma unroll
        for (int r = 0; r < 4; ++r) {
            float pm = fmaxf(s0[r], s1[r]);
            pm = fmaxf(pm, __shfl_xor(pm, 1, 16));
            pm = fmaxf(pm, __shfl_xor(pm, 2, 16));
            pm = fmaxf(pm, __shfl_xor(pm, 4, 16));
            pm = fmaxf(pm, __shfl_xor(pm, 8, 16));
            const float mn = fmaxf(m[r], pm);
            const float corr = __expf(m[r] - mn);
            m[r] = mn;
            const float p0 = __expf(s0[r] - mn);
            const float p1 = __expf(s1[r] - mn);
            s0[r] = p0; s1[r] = p1;
            float ps = p0 + p1;
            ps += __shfl_xor(ps, 1, 16);
            ps += __shfl_xor(ps, 2, 16);
            ps += __shfl_xor(ps, 4, 16);
            ps += __shfl_xor(ps, 8, 16);
            ls[r] = ls[r] * corr + ps;
            oacc[0][r] *= corr; oacc[1][r] *= corr;
            oacc[2][r] *= corr; oacc[3][r] *= corr;
        }
        // P -> LDS (wave-private; in-order within a wave, no barrier needed)
#pragma unroll
        for (int r = 0; r < 4; ++r) {
            p_lds[w][(lh * 4 + r) * 32 + lr] = f2bf(s0[r]);
            p_lds[w][(lh * 4 + r) * 32 + 16 + lr] = f2bf(s1[r]);
        }
        bf16x8 pa = *(const bf16x8*)&p_lds[w][lr * 32 + lh * 8];
#pragma unroll
        for (int dt = 0; dt < 4; ++dt) {
            bf16x8 vf = *(const bf16x8*)&vt[vhead + (size_t)(dt * 16 + lr) * 1024 + j0 + lh * 8];
            oacc[dt] = MFMA16(pa, vf, oacc[dt]);
        }
    }

    float inv[4];
#pragma unroll
    for (int r = 0; r < 4; ++r) inv[r] = 1.f / ls[r];
#pragma unroll
    for (int dt = 0; dt < 4; ++dt)
#pragma unroll
        for (int r = 0; r < 4; ++r) {
            const int row = qbase + lh * 4 + r;
            o[headoff + (size_t)row * 1024 + dt * 16 + lr] = f2bf(oacc[dt][r] * inv[r]);
        }
}

// ---------------------------------------------------------------------------
// fused residual + LayerNorm: x = LN(t + x); writes f32 x and bf16 xb
// ---------------------------------------------------------------------------
__global__ __launch_bounds__(256) void add_ln(const float* __restrict__ t,
                                              float* __restrict__ x,
                                              const float* __restrict__ g,
                                              const float* __restrict__ bb,
                                              ushort_t* __restrict__ xb) {
    const int row = blockIdx.x, tid = threadIdx.x;
    const int lane = tid & 63, w = tid >> 6;
    const size_t base = (size_t)row * 1024;
    float4 tv = ((const float4*)(t + base))[tid];
    float4 xv = ((const float4*)(x + base))[tid];
    float v0 = tv.x + xv.x, v1 = tv.y + xv.y, v2 = tv.z + xv.z, v3 = tv.w + xv.w;
    float s = v0 + v1 + v2 + v3;
    float sq = v0 * v0 + v1 * v1 + v2 * v2 + v3 * v3;
#pragma unroll
    for (int off = 32; off >= 1; off >>= 1) {
        s += __shfl_xor(s, off);
        sq += __shfl_xor(sq, off);
    }
    __shared__ float red[8];
    if (lane == 0) { red[w] = s; red[4 + w] = sq; }
    __syncthreads();
    s = red[0] + red[1] + red[2] + red[3];
    sq = red[4] + red[5] + red[6] + red[7];
    const float mu = s * (1.f / 1024.f);
    const float var = sq * (1.f / 1024.f) - mu * mu;
    const float rs = rsqrtf(var + 1e-6f);
    float4 gv = ((const float4*)g)[tid];
    float4 bv = ((const float4*)bb)[tid];
    float y0 = (v0 - mu) * rs * gv.x + bv.x;
    float y1 = (v1 - mu) * rs * gv.y + bv.y;
    float y2 = (v2 - mu) * rs * gv.z + bv.z;
    float y3 = (v3 - mu) * rs * gv.w + bv.w;
    float4 yo; yo.x = y0; yo.y = y1; yo.z = y2; yo.w = y3;
    ((float4*)(x + base))[tid] = yo;
    ushort4 hh;
    hh.x = f2bf(y0); hh.y = f2bf(y1); hh.z = f2bf(y2); hh.w = f2bf(y3);
    ((ushort4*)(xb + base))[tid] = hh;
}

// ---------------------------------------------------------------------------
extern "C" void kernel_launch(void* const* d_in, const int* in_sizes, int n_in,
                              void* d_out, int out_size, void* d_ws, size_t ws_size,
                              hipStream_t stream) {
    (void)in_sizes; (void)n_in; (void)out_size; (void)ws_size;
    const int B = 8, S = 1024, D = 1024, DFF = 4096, L = 2;
    const int M = B * S;  // 8192

    const float* x_in = (const float*)d_in[0];
    const float* Wq = (const float*)d_in[2];
    const float* bq = (const float*)d_in[3];
    const float* Wk = (const float*)d_in[4];
    const float* bk = (const float*)d_in[5];
    const float* Wv = (const float*)d_in[6];
    const float* bv = (const float*)d_in[7];
    const float* Wo = (const float*)d_in[8];
    const float* bo = (const float*)d_in[9];
    const float* W1 = (const float*)d_in[10];
    const float* b1 = (const float*)d_in[11];
    const float* W2 = (const float*)d_in[12];
    const float* b2 = (const float*)d_in[13];
    const float* ln1g = (const float*)d_in[14];
    const float* ln1b = (const float*)d_in[15];
    const float* ln2g = (const float*)d_in[16];
    const float* ln2b = (const float*)d_in[17];

    float* x = (float*)d_out;  // running f32 activation buffer
    char* ws = (char*)d_ws;
    const size_t MB = 1024 * 1024;
    ushort_t* wqkvT = (ushort_t*)(ws + 0 * MB);   // 12MB (2 layers x 3072x1024)
    ushort_t* woT = (ushort_t*)(ws + 12 * MB);    // 4MB
    ushort_t* w1T = (ushort_t*)(ws + 16 * MB);    // 16MB
    ushort_t* w2T = (ushort_t*)(ws + 32 * MB);    // 16MB
    ushort_t* xb  = (ushort_t*)(ws + 48 * MB);    // 16MB
    ushort_t* qb  = (ushort_t*)(ws + 64 * MB);    // 16MB
    ushort_t* kb  = (ushort_t*)(ws + 80 * MB);    // 16MB
    ushort_t* vtb = (ushort_t*)(ws + 96 * MB);    // 16MB  (B,H,DH,S)
    ushort_t* ob  = (ushort_t*)(ws + 112 * MB);   // 16MB
    ushort_t* hb  = (ushort_t*)(ws + 64 * MB);    // 64MB, reuses q/k/vt/o region
    float* t      = (float*)(ws + 128 * MB);      // 32MB f32

    init_x<<<M * D / 4 / 256, 256, 0, stream>>>(x_in, x, xb, M * D / 4);

    dim3 tb(32, 8);
    for (int l = 0; l < L; ++l) {
        const size_t wOff = (size_t)l * D * D;
        const size_t qkvOff = (size_t)l * 3 * D * D;
        transpose_convert<<<dim3(D / 32, D / 32), tb, 0, stream>>>(Wq + wOff, wqkvT + qkvOff, D, D);
        transpose_convert<<<dim3(D / 32, D / 32), tb, 0, stream>>>(Wk + wOff, wqkvT + qkvOff + (size_t)D * D, D, D);
        transpose_convert<<<dim3(D / 32, D / 32), tb, 0, stream>>>(Wv + wOff, wqkvT + qkvOff + 2 * (size_t)D * D, D, D);
        transpose_convert<<<dim3(D / 32, D / 32), tb, 0, stream>>>(Wo + wOff, woT + wOff, D, D);
        transpose_convert<<<dim3(DFF / 32, D / 32), tb, 0, stream>>>(W1 + (size_t)l * D * DFF, w1T + (size_t)l * D * DFF, D, DFF);
        transpose_convert<<<dim3(D / 32, DFF / 32), tb, 0, stream>>>(W2 + (size_t)l * DFF * D, w2T + (size_t)l * DFF * D, DFF, D);
    }

    const int gxQKV = 3 * D / 128, gyM = M / 128;   // 24 x 64
    const int gxP = D / 128;                        // 8
    const int gxF1 = DFF / 128;                     // 32

    for (int l = 0; l < L; ++l) {
        const size_t wOff = (size_t)l * D * D;
        const size_t bOff = (size_t)l * D;
        gemm_bt<2, 0><<<dim3(gxQKV * gyM), 256, 0, stream>>>(
            xb, wqkvT + (size_t)l * 3 * D * D, nullptr, nullptr, M, 3 * D, D, gxQKV,
            qb, kb, vtb, bq + bOff, bk + bOff, bv + bOff);
        attn_kernel<<<dim3(S / 64, B * 16), 256, 0, stream>>>(qb, kb, vtb, ob);
        gemm_bt<0, 0><<<dim3(gxP * gyM), 256, 0, stream>>>(
            ob, woT + wOff, bo + bOff, t, M, D, D, gxP,
            nullptr, nullptr, nullptr, nullptr, nullptr, nullptr);
        add_ln<<<M, 256, 0, stream>>>(t, x, ln1g + bOff, ln1b + bOff, xb);
        gemm_bt<1, 1><<<dim3(gxF1 * gyM), 256, 0, stream>>>(
            xb, w1T + (size_t)l * D * DFF, b1 + (size_t)l * DFF, hb, M, DFF, D, gxF1,
            nullptr, nullptr, nullptr, nullptr, nullptr, nullptr);
        gemm_bt<0, 0><<<dim3(gxP * gyM), 256, 0, stream>>>(
            hb, w2T + (size_t)l * DFF * D, b2 + bOff, t, M, D, DFF, gxP,
            nullptr, nullptr, nullptr, nullptr, nullptr, nullptr);
        add_ln<<<M, 256, 0, stream>>>(t, x, ln2g + bOff, ln2b + bOff, xb);
    }
}

// Round 3
// 880.056 us; speedup vs baseline: 1.3505x; 1.3505x over previous
//
#include <hip/hip_runtime.h>

typedef __attribute__((ext_vector_type(8))) short bf16x8;
typedef __attribute__((ext_vector_type(4))) float f32x4;
typedef unsigned short ushort_t;
typedef unsigned int uint32;

#define DEV __device__ __forceinline__

// round-to-nearest-even f32 -> bf16 (bits)
DEV ushort_t f2bf(float f) {
    uint32 u = __float_as_uint(f);
    uint32 r = (u + 0x7FFFu + ((u >> 16) & 1u)) >> 16;
    return (ushort_t)r;
}

#define MFMA16(a, b, c) __builtin_amdgcn_mfma_f32_16x16x32_bf16((a), (b), (c), 0, 0, 0)

DEV void gload_lds16(const void* g, void* l) {
    __builtin_amdgcn_global_load_lds((const __attribute__((address_space(1))) void*)g,
                                     (__attribute__((address_space(3))) void*)l,
                                     16, 0, 0);
}

// ---------------------------------------------------------------------------
// init: copy f32 x -> d_out (running x buffer) and bf16 xb
// ---------------------------------------------------------------------------
__global__ __launch_bounds__(256) void init_x(const float* __restrict__ xin,
                                              float* __restrict__ x,
                                              ushort_t* __restrict__ xb, int n4) {
    int i = blockIdx.x * 256 + threadIdx.x;
    if (i >= n4) return;
    float4 v = ((const float4*)xin)[i];
    ((float4*)x)[i] = v;
    ushort4 h;
    h.x = f2bf(v.x); h.y = f2bf(v.y); h.z = f2bf(v.z); h.w = f2bf(v.w);
    ((ushort4*)xb)[i] = h;
}

// ---------------------------------------------------------------------------
// transpose + convert: src (K x N f32, row-major) -> dst (N x K bf16)
// ---------------------------------------------------------------------------
__global__ __launch_bounds__(256) void transpose_convert(const float* __restrict__ src,
                                                         ushort_t* __restrict__ dst,
                                                         int K, int N) {
    __shared__ float tile[32][33];
    int tx = threadIdx.x, ty = threadIdx.y;  // (32,8)
    int nt = blockIdx.x * 32, kt = blockIdx.y * 32;
#pragma unroll
    for (int j = 0; j < 4; ++j)
        tile[ty + j * 8][tx] = src[(size_t)(kt + ty + j * 8) * N + nt + tx];
    __syncthreads();
#pragma unroll
    for (int j = 0; j < 4; ++j)
        dst[(size_t)(nt + ty + j * 8) * K + kt + tx] = f2bf(tile[tx][ty + j * 8]);
}

// ---------------------------------------------------------------------------
// GEMM: C[M,N] = A[M,K] @ BT[N,K]^T + bias (bf16 in, f32 acc)
// 128x128 tile, BK=32, 4 waves (2x2), each wave 64x64 = 4x4 16x16 frags.
// MODE: 0 = f32 out, 1 = bf16 out, 2 = fused QKV split (q scaled by 1/8,
//       k row-major bf16; v written transposed per-head into vt (B,H,DH,S)).
// 1D grid with XCD-aware bijective swizzle (m204).
// ---------------------------------------------------------------------------
template <int MODE, int RELU>
__global__ __launch_bounds__(256) void gemm_bt(const ushort_t* __restrict__ A,
                                               const ushort_t* __restrict__ BT,
                                               const float* __restrict__ bias,
                                               void* __restrict__ Cout,
                                               int M, int N, int K, int gx,
                                               ushort_t* __restrict__ qout,
                                               ushort_t* __restrict__ kout,
                                               ushort_t* __restrict__ vtout,
                                               const float* __restrict__ bq,
                                               const float* __restrict__ bk,
                                               const float* __restrict__ bv) {
    __shared__ ushort_t a_lds[128 * 32];
    __shared__ ushort_t b_lds[128 * 32];
    // XCD-aware bijective swizzle: contiguous chunks per XCD
    const int nwg = gridDim.x;
    const int q8 = nwg >> 3, r8 = nwg & 7;
    const int xcd = blockIdx.x & 7, idx = blockIdx.x >> 3;
    const int swz = (xcd < r8 ? xcd * (q8 + 1) : r8 * (q8 + 1) + (xcd - r8) * q8) + idx;
    const int bxi = swz % gx, byi = swz / gx;

    const int tid = threadIdx.x;
    const int w = tid >> 6, lane = tid & 63;
    const int wm = w >> 1, wn = w & 1;
    const int lr = lane & 15, lh = lane >> 4;
    const int row0 = byi * 128, col0 = bxi * 128;

    f32x4 acc[4][4] = {};

    const int e0 = tid * 8;          // LDS elem offset, chunk 0 (16B per lane)
    const int r0 = e0 >> 5, c0 = e0 & 31;
    const int e1 = e0 + 2048;        // chunk 1
    const int r1 = r0 + 64;

    const ushort_t* Ab = A + (size_t)row0 * K;
    const ushort_t* Bb = BT + (size_t)col0 * K;

    for (int k0 = 0; k0 < K; k0 += 32) {
        __syncthreads();
        gload_lds16(Ab + (size_t)r0 * K + k0 + c0, &a_lds[e0]);
        gload_lds16(Ab + (size_t)r1 * K + k0 + c0, &a_lds[e1]);
        gload_lds16(Bb + (size_t)r0 * K + k0 + c0, &b_lds[e0]);
        gload_lds16(Bb + (size_t)r1 * K + k0 + c0, &b_lds[e1]);
        __syncthreads();  // drains vmcnt (global_load_lds) + barrier

        bf16x8 af[4], bfr[4];
#pragma unroll
        for (int mi = 0; mi < 4; ++mi)
            af[mi] = *(const bf16x8*)&a_lds[(wm * 64 + mi * 16 + lr) * 32 + lh * 8];
#pragma unroll
        for (int ni = 0; ni < 4; ++ni)
            bfr[ni] = *(const bf16x8*)&b_lds[(wn * 64 + ni * 16 + lr) * 32 + lh * 8];
#pragma unroll
        for (int mi = 0; mi < 4; ++mi)
#pragma unroll
            for (int ni = 0; ni < 4; ++ni)
                acc[mi][ni] = MFMA16(af[mi], bfr[ni], acc[mi][ni]);
    }

#pragma unroll
    for (int mi = 0; mi < 4; ++mi) {
#pragma unroll
        for (int ni = 0; ni < 4; ++ni) {
            const int col = col0 + wn * 64 + ni * 16 + lr;
            const int rowb = row0 + wm * 64 + mi * 16 + lh * 4;
            if (MODE == 2) {
                if (col < 1024) {  // q, pre-scaled by 1/8 (exact in bf16)
                    const float bvv = bq[col];
#pragma unroll
                    for (int r = 0; r < 4; ++r)
                        qout[(size_t)(rowb + r) * 1024 + col] = f2bf((acc[mi][ni][r] + bvv) * 0.125f);
                } else if (col < 2048) {
                    const int c = col - 1024;
                    const float bvv = bk[c];
#pragma unroll
                    for (int r = 0; r < 4; ++r)
                        kout[(size_t)(rowb + r) * 1024 + c] = f2bf(acc[mi][ni][r] + bvv);
                } else {
                    const int d = col - 2048;
                    const int h = d >> 6, dd = d & 63;
                    const int b = rowb >> 10, s = rowb & 1023;
                    const float bvv = bv[d];
                    ushort4 h4;
                    h4.x = f2bf(acc[mi][ni][0] + bvv);
                    h4.y = f2bf(acc[mi][ni][1] + bvv);
                    h4.z = f2bf(acc[mi][ni][2] + bvv);
                    h4.w = f2bf(acc[mi][ni][3] + bvv);
                    *(ushort4*)&vtout[(((size_t)(b * 16 + h) * 64 + dd) << 10) + s] = h4;
                }
            } else {
                const float bvv = bias[col];
#pragma unroll
                for (int r = 0; r < 4; ++r) {
                    float val = acc[mi][ni][r] + bvv;
                    if (RELU) val = fmaxf(val, 0.f);
                    if (MODE == 1)
                        ((ushort_t*)Cout)[(size_t)(rowb + r) * N + col] = f2bf(val);
                    else
                        ((float*)Cout)[(size_t)(rowb + r) * N + col] = val;
                }
            }
        }
    }
}

// ---------------------------------------------------------------------------
// fused causal flash attention. Grid: (bh=128, qt=16) so same-head blocks land
// on the same XCD (L2 locality for K/V). Block = 4 waves x 16 q rows = 64 rows.
// K and V^T staged in LDS per 64-key tile (XOR-swizzled), async-split staging:
// next tile's global loads issued before compute. q is pre-scaled by 1/8.
// ---------------------------------------------------------------------------
__global__ __launch_bounds__(256) void attn_kernel(const ushort_t* __restrict__ q,
                                                   const ushort_t* __restrict__ k,
                                                   const ushort_t* __restrict__ vt,
                                                   ushort_t* __restrict__ o) {
    __shared__ ushort_t ktile[64 * 64];     // 8KB, swizzled rows of 128B
    __shared__ ushort_t vtile[64 * 64];     // 8KB, V^T (dh x key), swizzled
    __shared__ ushort_t p_lds[4][16 * 64];  // 8KB, per-wave P, swizzled

    const int bh = blockIdx.x;
    const int b = bh >> 4, h = bh & 15;
    const int qt = blockIdx.y;
    const int tid = threadIdx.x, w = tid >> 6, lane = tid & 63;
    const int lr = lane & 15, lh = lane >> 4;
    const int qbase = qt * 64 + w * 16;
    const size_t headoff = (size_t)b * 1024 * 1024 + h * 64;
    const size_t vhead = (size_t)(b * 16 + h) << 16;  // *64*1024

    bf16x8 qf[2];
#pragma unroll
    for (int ks = 0; ks < 2; ++ks)
        qf[ks] = *(const bf16x8*)&q[headoff + (size_t)(qbase + lr) * 1024 + ks * 32 + lh * 8];

    f32x4 oacc[4] = {};
    float m[4] = {-INFINITY, -INFINITY, -INFINITY, -INFINITY};
    float ls[4] = {0.f, 0.f, 0.f, 0.f};

    // staging geometry: 256 threads, rows of 128B (8 lanes x 16B), 2 passes
    const int srow = tid >> 3;            // 0..31
    const int scolb = (tid & 7) * 16;     // byte col within 128B row
    const int swz0 = ((srow & 7) << 4);   // row XOR mask (same for srow, srow+32)
    char* const kbase = (char*)ktile;
    char* const vbase = (char*)vtile;
    char* const kw0 = kbase + srow * 128 + (scolb ^ swz0);
    char* const kw1 = kbase + (srow + 32) * 128 + (scolb ^ swz0);
    char* const vw0 = vbase + srow * 128 + (scolb ^ swz0);
    char* const vw1 = vbase + (srow + 32) * 128 + (scolb ^ swz0);
    const ushort_t* kg = k + headoff + (size_t)srow * 1024 + (tid & 7) * 8;
    const ushort_t* vg = vt + vhead + (size_t)srow * 1024 + (tid & 7) * 8;

    const int jmaxw = qbase + 15;       // per-wave causal bound
    const int jend = qt * 64 + 63;      // block bound

    bf16x8 sk0 = *(const bf16x8*)&kg[0];
    bf16x8 sk1 = *(const bf16x8*)&kg[32 * 1024];
    bf16x8 sv0 = *(const bf16x8*)&vg[0];
    bf16x8 sv1 = *(const bf16x8*)&vg[32 * 1024];

    for (int j0 = 0; j0 <= jend; j0 += 64) {
        __syncthreads();  // LDS safe to overwrite
        *(bf16x8*)kw0 = sk0;
        *(bf16x8*)kw1 = sk1;
        *(bf16x8*)vw0 = sv0;
        *(bf16x8*)vw1 = sv1;
        __syncthreads();
        // async-split: issue next tile's global loads now, consume next iter
        if (j0 + 64 <= jend) {
            sk0 = *(const bf16x8*)&kg[(size_t)(j0 + 64) * 1024];
            sk1 = *(const bf16x8*)&kg[(size_t)(j0 + 64) * 1024 + 32 * 1024];
            sv0 = *(const bf16x8*)&vg[j0 + 64];
            sv1 = *(const bf16x8*)&vg[32 * 1024 + j0 + 64];
        }

        if (j0 <= jmaxw) {
            // QK^T: s[kt] covers keys j0+kt*16+lr, q rows qbase+4lh+r
            f32x4 s[4] = {{0,0,0,0},{0,0,0,0},{0,0,0,0},{0,0,0,0}};
#pragma unroll
            for (int kt = 0; kt < 4; ++kt) {
                const int row = kt * 16 + lr;
                const int rswz = ((row & 7) << 4);
#pragma unroll
                for (int ks = 0; ks < 2; ++ks) {
                    bf16x8 kf = *(const bf16x8*)(kbase + row * 128 + ((ks * 64 + lh * 16) ^ rswz));
                    s[kt] = MFMA16(qf[ks], kf, s[kt]);
                }
            }
            if (j0 + 63 > qbase) {  // diagonal tile (wave-uniform): mask
#pragma unroll
                for (int kt = 0; kt < 4; ++kt)
#pragma unroll
                    for (int r = 0; r < 4; ++r)
                        s[kt][r] = ((j0 + kt * 16 + lr) <= (qbase + lh * 4 + r)) ? s[kt][r] : -1e9f;
            }
            // online softmax: row q = qbase+4lh+r lives in 16-lane groups
#pragma unroll
            for (int r = 0; r < 4; ++r) {
                float pm = fmaxf(fmaxf(s[0][r], s[1][r]), fmaxf(s[2][r], s[3][r]));
                pm = fmaxf(pm, __shfl_xor(pm, 1, 16));
                pm = fmaxf(pm, __shfl_xor(pm, 2, 16));
                pm = fmaxf(pm, __shfl_xor(pm, 4, 16));
                pm = fmaxf(pm, __shfl_xor(pm, 8, 16));
                const float mn = fmaxf(m[r], pm);
                const float corr = __expf(m[r] - mn);
                m[r] = mn;
                float p0 = __expf(s[0][r] - mn);
                float p1 = __expf(s[1][r] - mn);
                float p2 = __expf(s[2][r] - mn);
                float p3 = __expf(s[3][r] - mn);
                s[0][r] = p0; s[1][r] = p1; s[2][r] = p2; s[3][r] = p3;
                float ps = (p0 + p1) + (p2 + p3);
                ps += __shfl_xor(ps, 1, 16);
                ps += __shfl_xor(ps, 2, 16);
                ps += __shfl_xor(ps, 4, 16);
                ps += __shfl_xor(ps, 8, 16);
                ls[r] = ls[r] * corr + ps;
                oacc[0][r] *= corr; oacc[1][r] *= corr;
                oacc[2][r] *= corr; oacc[3][r] *= corr;
            }
            // P -> wave-private LDS (swizzled), then A-frag reads
            char* const pb = (char*)p_lds[w];
#pragma unroll
            for (int r = 0; r < 4; ++r) {
                const int qrow = lh * 4 + r;
                const int qswz = ((qrow & 7) << 4);
#pragma unroll
                for (int kt = 0; kt < 4; ++kt)
                    *(ushort_t*)(pb + qrow * 128 + ((kt * 32 + lr * 2) ^ qswz)) = f2bf(s[kt][r]);
            }
            const int pswz = ((lr & 7) << 4);
            bf16x8 pa0 = *(const bf16x8*)(pb + lr * 128 + ((lh * 16) ^ pswz));
            bf16x8 pa1 = *(const bf16x8*)(pb + lr * 128 + ((64 + lh * 16) ^ pswz));
#pragma unroll
            for (int dt = 0; dt < 4; ++dt) {
                const int vrow = dt * 16 + lr;
                const int vswz = ((vrow & 7) << 4);
                bf16x8 vf0 = *(const bf16x8*)(vbase + vrow * 128 + ((lh * 16) ^ vswz));
                oacc[dt] = MFMA16(pa0, vf0, oacc[dt]);
                bf16x8 vf1 = *(const bf16x8*)(vbase + vrow * 128 + ((64 + lh * 16) ^ vswz));
                oacc[dt] = MFMA16(pa1, vf1, oacc[dt]);
            }
        }
    }

    float inv[4];
#pragma unroll
    for (int r = 0; r < 4; ++r) inv[r] = 1.f / ls[r];
#pragma unroll
    for (int dt = 0; dt < 4; ++dt)
#pragma unroll
        for (int r = 0; r < 4; ++r) {
            const int row = qbase + lh * 4 + r;
            o[headoff + (size_t)row * 1024 + dt * 16 + lr] = f2bf(oacc[dt][r] * inv[r]);
        }
}

// ---------------------------------------------------------------------------
// fused residual + LayerNorm: x = LN(t + x); writes f32 x and bf16 xb
// ---------------------------------------------------------------------------
__global__ __launch_bounds__(256) void add_ln(const float* __restrict__ t,
                                              float* __restrict__ x,
                                              const float* __restrict__ g,
                                              const float* __restrict__ bb,
                                              ushort_t* __restrict__ xb) {
    const int row = blockIdx.x, tid = threadIdx.x;
    const int lane = tid & 63, w = tid >> 6;
    const size_t base = (size_t)row * 1024;
    float4 tv = ((const float4*)(t + base))[tid];
    float4 xv = ((const float4*)(x + base))[tid];
    float v0 = tv.x + xv.x, v1 = tv.y + xv.y, v2 = tv.z + xv.z, v3 = tv.w + xv.w;
    float s = v0 + v1 + v2 + v3;
    float sq = v0 * v0 + v1 * v1 + v2 * v2 + v3 * v3;
#pragma unroll
    for (int off = 32; off >= 1; off >>= 1) {
        s += __shfl_xor(s, off);
        sq += __shfl_xor(sq, off);
    }
    __shared__ float red[8];
    if (lane == 0) { red[w] = s; red[4 + w] = sq; }
    __syncthreads();
    s = red[0] + red[1] + red[2] + red[3];
    sq = red[4] + red[5] + red[6] + red[7];
    const float mu = s * (1.f / 1024.f);
    const float var = sq * (1.f / 1024.f) - mu * mu;
    const float rs = rsqrtf(var + 1e-6f);
    float4 gv = ((const float4*)g)[tid];
    float4 bv = ((const float4*)bb)[tid];
    float y0 = (v0 - mu) * rs * gv.x + bv.x;
    float y1 = (v1 - mu) * rs * gv.y + bv.y;
    float y2 = (v2 - mu) * rs * gv.z + bv.z;
    float y3 = (v3 - mu) * rs * gv.w + bv.w;
    float4 yo; yo.x = y0; yo.y = y1; yo.z = y2; yo.w = y3;
    ((float4*)(x + base))[tid] = yo;
    ushort4 hh;
    hh.x = f2bf(y0); hh.y = f2bf(y1); hh.z = f2bf(y2); hh.w = f2bf(y3);
    ((ushort4*)(xb + base))[tid] = hh;
}

// ---------------------------------------------------------------------------
extern "C" void kernel_launch(void* const* d_in, const int* in_sizes, int n_in,
                              void* d_out, int out_size, void* d_ws, size_t ws_size,
                              hipStream_t stream) {
    (void)in_sizes; (void)n_in; (void)out_size; (void)ws_size;
    const int B = 8, S = 1024, D = 1024, DFF = 4096, L = 2;
    const int M = B * S;  // 8192

    const float* x_in = (const float*)d_in[0];
    const float* Wq = (const float*)d_in[2];
    const float* bq = (const float*)d_in[3];
    const float* Wk = (const float*)d_in[4];
    const float* bk = (const float*)d_in[5];
    const float* Wv = (const float*)d_in[6];
    const float* bv = (const float*)d_in[7];
    const float* Wo = (const float*)d_in[8];
    const float* bo = (const float*)d_in[9];
    const float* W1 = (const float*)d_in[10];
    const float* b1 = (const float*)d_in[11];
    const float* W2 = (const float*)d_in[12];
    const float* b2 = (const float*)d_in[13];
    const float* ln1g = (const float*)d_in[14];
    const float* ln1b = (const float*)d_in[15];
    const float* ln2g = (const float*)d_in[16];
    const float* ln2b = (const float*)d_in[17];

    float* x = (float*)d_out;  // running f32 activation buffer
    char* ws = (char*)d_ws;
    const size_t MB = 1024 * 1024;
    ushort_t* wqkvT = (ushort_t*)(ws + 0 * MB);   // 12MB (2 layers x 3072x1024)
    ushort_t* woT = (ushort_t*)(ws + 12 * MB);    // 4MB
    ushort_t* w1T = (ushort_t*)(ws + 16 * MB);    // 16MB
    ushort_t* w2T = (ushort_t*)(ws + 32 * MB);    // 16MB
    ushort_t* xb  = (ushort_t*)(ws + 48 * MB);    // 16MB
    ushort_t* qb  = (ushort_t*)(ws + 64 * MB);    // 16MB
    ushort_t* kb  = (ushort_t*)(ws + 80 * MB);    // 16MB
    ushort_t* vtb = (ushort_t*)(ws + 96 * MB);    // 16MB  (B,H,DH,S)
    ushort_t* ob  = (ushort_t*)(ws + 112 * MB);   // 16MB
    ushort_t* hb  = (ushort_t*)(ws + 64 * MB);    // 64MB, reuses q/k/vt/o region
    float* t      = (float*)(ws + 128 * MB);      // 32MB f32

    init_x<<<M * D / 4 / 256, 256, 0, stream>>>(x_in, x, xb, M * D / 4);

    dim3 tb(32, 8);
    for (int l = 0; l < L; ++l) {
        const size_t wOff = (size_t)l * D * D;
        const size_t qkvOff = (size_t)l * 3 * D * D;
        transpose_convert<<<dim3(D / 32, D / 32), tb, 0, stream>>>(Wq + wOff, wqkvT + qkvOff, D, D);
        transpose_convert<<<dim3(D / 32, D / 32), tb, 0, stream>>>(Wk + wOff, wqkvT + qkvOff + (size_t)D * D, D, D);
        transpose_convert<<<dim3(D / 32, D / 32), tb, 0, stream>>>(Wv + wOff, wqkvT + qkvOff + 2 * (size_t)D * D, D, D);
        transpose_convert<<<dim3(D / 32, D / 32), tb, 0, stream>>>(Wo + wOff, woT + wOff, D, D);
        transpose_convert<<<dim3(DFF / 32, D / 32), tb, 0, stream>>>(W1 + (size_t)l * D * DFF, w1T + (size_t)l * D * DFF, D, DFF);
        transpose_convert<<<dim3(D / 32, DFF / 32), tb, 0, stream>>>(W2 + (size_t)l * DFF * D, w2T + (size_t)l * DFF * D, DFF, D);
    }

    const int gxQKV = 3 * D / 128, gyM = M / 128;   // 24 x 64
    const int gxP = D / 128;                        // 8
    const int gxF1 = DFF / 128;                     // 32

    for (int l = 0; l < L; ++l) {
        const size_t wOff = (size_t)l * D * D;
        const size_t bOff = (size_t)l * D;
        gemm_bt<2, 0><<<dim3(gxQKV * gyM), 256, 0, stream>>>(
            xb, wqkvT + (size_t)l * 3 * D * D, nullptr, nullptr, M, 3 * D, D, gxQKV,
            qb, kb, vtb, bq + bOff, bk + bOff, bv + bOff);
        attn_kernel<<<dim3(B * 16, S / 64), 256, 0, stream>>>(qb, kb, vtb, ob);
        gemm_bt<0, 0><<<dim3(gxP * gyM), 256, 0, stream>>>(
            ob, woT + wOff, bo + bOff, t, M, D, D, gxP,
            nullptr, nullptr, nullptr, nullptr, nullptr, nullptr);
        add_ln<<<M, 256, 0, stream>>>(t, x, ln1g + bOff, ln1b + bOff, xb);
        gemm_bt<1, 1><<<dim3(gxF1 * gyM), 256, 0, stream>>>(
            xb, w1T + (size_t)l * D * DFF, b1 + (size_t)l * DFF, hb, M, DFF, D, gxF1,
            nullptr, nullptr, nullptr, nullptr, nullptr, nullptr);
        gemm_bt<0, 0><<<dim3(gxP * gyM), 256, 0, stream>>>(
            hb, w2T + (size_t)l * DFF * D, b2 + bOff, t, M, D, DFF, gxP,
            nullptr, nullptr, nullptr, nullptr, nullptr, nullptr);
        add_ln<<<M, 256, 0, stream>>>(t, x, ln2g + bOff, ln2b + bOff, xb);
    }
}

// Round 4
// 768.471 us; speedup vs baseline: 1.5465x; 1.1452x over previous
//
#include <hip/hip_runtime.h>

typedef __attribute__((ext_vector_type(8))) short bf16x8;
typedef __attribute__((ext_vector_type(4))) float f32x4;
typedef unsigned short ushort_t;
typedef unsigned int uint32;

#define DEV __device__ __forceinline__

// round-to-nearest-even f32 -> bf16 (bits)
DEV ushort_t f2bf(float f) {
    uint32 u = __float_as_uint(f);
    uint32 r = (u + 0x7FFFu + ((u >> 16) & 1u)) >> 16;
    return (ushort_t)r;
}

#define MFMA16(a, b, c) __builtin_amdgcn_mfma_f32_16x16x32_bf16((a), (b), (c), 0, 0, 0)

DEV void gload_lds16(const void* g, void* l) {
    __builtin_amdgcn_global_load_lds((const __attribute__((address_space(1))) void*)g,
                                     (__attribute__((address_space(3))) void*)l,
                                     16, 0, 0);
}

// ---------------------------------------------------------------------------
// init: copy f32 x -> d_out (running x buffer) and bf16 xb
// ---------------------------------------------------------------------------
__global__ __launch_bounds__(256) void init_x(const float* __restrict__ xin,
                                              float* __restrict__ x,
                                              ushort_t* __restrict__ xb, int n4) {
    int i = blockIdx.x * 256 + threadIdx.x;
    if (i >= n4) return;
    float4 v = ((const float4*)xin)[i];
    ((float4*)x)[i] = v;
    ushort4 h;
    h.x = f2bf(v.x); h.y = f2bf(v.y); h.z = f2bf(v.z); h.w = f2bf(v.w);
    ((ushort4*)xb)[i] = h;
}

// ---------------------------------------------------------------------------
// transpose + convert: src (K x N f32, row-major) -> dst (N x K bf16)
// ---------------------------------------------------------------------------
__global__ __launch_bounds__(256) void transpose_convert(const float* __restrict__ src,
                                                         ushort_t* __restrict__ dst,
                                                         int K, int N) {
    __shared__ float tile[32][33];
    int tx = threadIdx.x, ty = threadIdx.y;  // (32,8)
    int nt = blockIdx.x * 32, kt = blockIdx.y * 32;
#pragma unroll
    for (int j = 0; j < 4; ++j)
        tile[ty + j * 8][tx] = src[(size_t)(kt + ty + j * 8) * N + nt + tx];
    __syncthreads();
#pragma unroll
    for (int j = 0; j < 4; ++j)
        dst[(size_t)(nt + ty + j * 8) * K + kt + tx] = f2bf(tile[tx][ty + j * 8]);
}

// ---------------------------------------------------------------------------
// 8-phase GEMM (m201 template, plain HIP): C[M,N] = A[M,K] @ BT[N,K]^T + bias
// BM x 256 tile, BK=64, 8 waves (2M x 4N), per-wave (BM/2) x 64 C.
// Double-buffered LDS (2 K-tiles), XOR3-swizzled (conflict-free b128 reads,
// applied via pre-swizzled global source since global_load_lds dest is linear).
// Counted vmcnt(4) once per K-tile (never 0 in steady state); raw s_barrier;
// setprio around MFMA clusters.
// MODE: 0 = f32 out, 1 = bf16 out (+RELU), 2 = fused QKV split.
// ---------------------------------------------------------------------------
template <int BM, int MODE, int RELU>
__global__ __launch_bounds__(512, 2) void gemm8p(const ushort_t* __restrict__ A,
                                                 const ushort_t* __restrict__ BT,
                                                 const float* __restrict__ bias,
                                                 void* __restrict__ Cout,
                                                 int M, int N, int K, int gx,
                                                 ushort_t* __restrict__ qout,
                                                 ushort_t* __restrict__ kout,
                                                 ushort_t* __restrict__ vtout,
                                                 const float* __restrict__ bq,
                                                 const float* __restrict__ bk,
                                                 const float* __restrict__ bv) {
    constexpr int AH = BM / 128;    // # of 128-row A halves
    constexpr int MREP = BM / 32;   // M frags per wave
    constexpr int MPP = MREP / 4;   // M frags per phase
    __shared__ ushort_t lds[2][(BM + 256) * 64];

    // XCD-aware bijective swizzle (m204)
    const int nwg = gridDim.x;
    const int q8 = nwg >> 3, r8 = nwg & 7;
    const int xcd = blockIdx.x & 7, idx = blockIdx.x >> 3;
    const int swz = (xcd < r8 ? xcd * (q8 + 1) : r8 * (q8 + 1) + (xcd - r8) * q8) + idx;
    const int bxi = swz % gx, byi = swz / gx;

    const int tid = threadIdx.x;
    const int w = tid >> 6, lane = tid & 63;
    const int wr = w >> 2, wc = w & 3;
    const int lr = lane & 15, lh = lane >> 4;
    const int row0 = byi * BM, col0 = bxi * 256;

    f32x4 acc[MREP][4] = {};

    const ushort_t* __restrict__ Ab = A + (size_t)row0 * K;
    const ushort_t* __restrict__ Bb = BT + (size_t)col0 * K;
    const int nt = K >> 6;

    // staging geometry: per 128-row half, 8 waves x 2 instr x 1KB; source is
    // pre-swizzled (colU ^= row&7) so linear LDS dest + swizzled read agree.
    const int sr8 = lane & 7;             // unused name guard
    const int r8l = lane >> 3;            // 0..7 row within 8-row block
    const int cu = (lane & 7) ^ r8l;      // swizzled col unit (16B)

    auto stage_half = [&](const ushort_t* src, ushort_t* lbase) {
#pragma unroll
        for (int i = 0; i < 2; ++i) {
            const int rowi = (w * 2 + i) * 8 + r8l;
            gload_lds16(src + (size_t)rowi * K + cu * 8, lbase + (w * 2 + i) * 512 + lane * 8);
        }
    };
    auto Ahalf = [&](int buf, int h) -> ushort_t* { return &lds[buf][h * 8192]; };
    auto Bhalf = [&](int buf, int h) -> ushort_t* { return &lds[buf][BM * 64 + h * 8192]; };
    auto stA = [&](int kt, int h, int buf) {
        stage_half(Ab + (size_t)h * 128 * K + (size_t)kt * 64, Ahalf(buf, h));
    };
    auto stB = [&](int kt, int h, int buf) {
        stage_half(Bb + (size_t)h * 128 * K + (size_t)kt * 64, Bhalf(buf, h));
    };

    // prologue: tile 0 (A+B) + B halves of tile 1; vmcnt(4) completes tile 0
    stB(0, 0, 0); stB(0, 1, 0);
    stA(0, 0, 0); if (AH == 2) stA(0, 1, 0);
    stB(1, 0, 1); stB(1, 1, 1);
    asm volatile("s_waitcnt vmcnt(4)" ::: "memory");
    __builtin_amdgcn_sched_barrier(0);
    __builtin_amdgcn_s_barrier();

    for (int t = 0; t < nt; ++t) {
        const int cb = t & 1, nb = cb ^ 1;
        bf16x8 bfrag[4][2];
#pragma unroll
        for (int p = 0; p < 4; ++p) {
            // --- ds-reads for this phase ---
            if (p == 0) {
#pragma unroll
                for (int ni = 0; ni < 4; ++ni) {
                    const int br = wc * 64 + ni * 16 + lr;
                    const ushort_t* bh = Bhalf(cb, br >> 7);
                    const int rr = br & 127;
#pragma unroll
                    for (int ks = 0; ks < 2; ++ks)
                        bfrag[ni][ks] = *(const bf16x8*)&bh[rr * 64 + (((ks * 4 + lh) ^ (rr & 7)) * 8)];
                }
            }
            bf16x8 af[MPP][2];
#pragma unroll
            for (int mm = 0; mm < MPP; ++mm) {
                const int fr = wr * (BM / 2) + (p * MPP + mm) * 16 + lr;
                const ushort_t* ah = Ahalf(cb, fr >> 7);
                const int rr = fr & 127;
#pragma unroll
                for (int ks = 0; ks < 2; ++ks)
                    af[mm][ks] = *(const bf16x8*)&ah[rr * 64 + (((ks * 4 + lh) ^ (rr & 7)) * 8)];
            }
            // --- stage one half-tile ---
            if (p == 0) { if (t + 1 < nt) stA(t + 1, 0, nb); }
            else if (p == 1) { if (AH == 2 && t + 1 < nt) stA(t + 1, 1, nb); }
            else if (p == 2) { if (t + 2 < nt) stB(t + 2, 0, cb); }
            else {
                if (t + 2 < nt) {
                    stB(t + 2, 1, cb);
                    asm volatile("s_waitcnt vmcnt(4)" ::: "memory");
                } else if (t + 1 < nt) {
                    asm volatile("s_waitcnt vmcnt(0)" ::: "memory");
                }
            }
            __builtin_amdgcn_sched_barrier(0);
            __builtin_amdgcn_s_barrier();
            asm volatile("s_waitcnt lgkmcnt(0)" ::: "memory");
            __builtin_amdgcn_sched_barrier(0);
            __builtin_amdgcn_s_setprio(1);
#pragma unroll
            for (int mm = 0; mm < MPP; ++mm)
#pragma unroll
                for (int ni = 0; ni < 4; ++ni)
#pragma unroll
                    for (int ks = 0; ks < 2; ++ks)
                        acc[p * MPP + mm][ni] = MFMA16(af[mm][ks], bfrag[ni][ks], acc[p * MPP + mm][ni]);
            __builtin_amdgcn_s_setprio(0);
            __builtin_amdgcn_sched_barrier(0);
            __builtin_amdgcn_s_barrier();
        }
    }
    (void)sr8; (void)M;

    // epilogue
#pragma unroll
    for (int mi = 0; mi < MREP; ++mi) {
#pragma unroll
        for (int ni = 0; ni < 4; ++ni) {
            const int col = col0 + wc * 64 + ni * 16 + lr;
            const int rowb = row0 + wr * (BM / 2) + mi * 16 + lh * 4;
            if (MODE == 2) {
                if (col < 1024) {  // q, pre-scaled by 1/8 (exact in bf16)
                    const float bvv = bq[col];
#pragma unroll
                    for (int r = 0; r < 4; ++r)
                        qout[(size_t)(rowb + r) * 1024 + col] = f2bf((acc[mi][ni][r] + bvv) * 0.125f);
                } else if (col < 2048) {
                    const int c = col - 1024;
                    const float bvv = bk[c];
#pragma unroll
                    for (int r = 0; r < 4; ++r)
                        kout[(size_t)(rowb + r) * 1024 + c] = f2bf(acc[mi][ni][r] + bvv);
                } else {
                    const int d = col - 2048;
                    const int h = d >> 6, dd = d & 63;
                    const int b = rowb >> 10, s = rowb & 1023;
                    const float bvv = bv[d];
                    ushort4 h4;
                    h4.x = f2bf(acc[mi][ni][0] + bvv);
                    h4.y = f2bf(acc[mi][ni][1] + bvv);
                    h4.z = f2bf(acc[mi][ni][2] + bvv);
                    h4.w = f2bf(acc[mi][ni][3] + bvv);
                    *(ushort4*)&vtout[(((size_t)(b * 16 + h) * 64 + dd) << 10) + s] = h4;
                }
            } else {
                const float bvv = bias[col];
#pragma unroll
                for (int r = 0; r < 4; ++r) {
                    float val = acc[mi][ni][r] + bvv;
                    if (RELU) val = fmaxf(val, 0.f);
                    if (MODE == 1)
                        ((ushort_t*)Cout)[(size_t)(rowb + r) * N + col] = f2bf(val);
                    else
                        ((float*)Cout)[(size_t)(rowb + r) * N + col] = val;
                }
            }
        }
    }
}

// ---------------------------------------------------------------------------
// fused causal flash attention. Grid: (bh=128, qt=16) so same-head blocks land
// on the same XCD (L2 locality for K/V). Block = 4 waves x 16 q rows = 64 rows.
// K and V^T staged in LDS per 64-key tile (XOR-swizzled), async-split staging:
// next tile's global loads issued before compute. q is pre-scaled by 1/8.
// ---------------------------------------------------------------------------
__global__ __launch_bounds__(256) void attn_kernel(const ushort_t* __restrict__ q,
                                                   const ushort_t* __restrict__ k,
                                                   const ushort_t* __restrict__ vt,
                                                   ushort_t* __restrict__ o) {
    __shared__ ushort_t ktile[64 * 64];     // 8KB, swizzled rows of 128B
    __shared__ ushort_t vtile[64 * 64];     // 8KB, V^T (dh x key), swizzled
    __shared__ ushort_t p_lds[4][16 * 64];  // 8KB, per-wave P, swizzled

    const int bh = blockIdx.x;
    const int b = bh >> 4, h = bh & 15;
    const int qt = blockIdx.y;
    const int tid = threadIdx.x, w = tid >> 6, lane = tid & 63;
    const int lr = lane & 15, lh = lane >> 4;
    const int qbase = qt * 64 + w * 16;
    const size_t headoff = (size_t)b * 1024 * 1024 + h * 64;
    const size_t vhead = (size_t)(b * 16 + h) << 16;  // *64*1024

    bf16x8 qf[2];
#pragma unroll
    for (int ks = 0; ks < 2; ++ks)
        qf[ks] = *(const bf16x8*)&q[headoff + (size_t)(qbase + lr) * 1024 + ks * 32 + lh * 8];

    f32x4 oacc[4] = {};
    float m[4] = {-INFINITY, -INFINITY, -INFINITY, -INFINITY};
    float ls[4] = {0.f, 0.f, 0.f, 0.f};

    // staging geometry: 256 threads, rows of 128B (8 lanes x 16B), 2 passes
    const int srow = tid >> 3;            // 0..31
    const int scolb = (tid & 7) * 16;     // byte col within 128B row
    const int swz0 = ((srow & 7) << 4);   // row XOR mask (same for srow, srow+32)
    char* const kbase = (char*)ktile;
    char* const vbase = (char*)vtile;
    char* const kw0 = kbase + srow * 128 + (scolb ^ swz0);
    char* const kw1 = kbase + (srow + 32) * 128 + (scolb ^ swz0);
    char* const vw0 = vbase + srow * 128 + (scolb ^ swz0);
    char* const vw1 = vbase + (srow + 32) * 128 + (scolb ^ swz0);
    const ushort_t* kg = k + headoff + (size_t)srow * 1024 + (tid & 7) * 8;
    const ushort_t* vg = vt + vhead + (size_t)srow * 1024 + (tid & 7) * 8;

    const int jmaxw = qbase + 15;       // per-wave causal bound
    const int jend = qt * 64 + 63;      // block bound

    bf16x8 sk0 = *(const bf16x8*)&kg[0];
    bf16x8 sk1 = *(const bf16x8*)&kg[32 * 1024];
    bf16x8 sv0 = *(const bf16x8*)&vg[0];
    bf16x8 sv1 = *(const bf16x8*)&vg[32 * 1024];

    for (int j0 = 0; j0 <= jend; j0 += 64) {
        __syncthreads();  // LDS safe to overwrite
        *(bf16x8*)kw0 = sk0;
        *(bf16x8*)kw1 = sk1;
        *(bf16x8*)vw0 = sv0;
        *(bf16x8*)vw1 = sv1;
        __syncthreads();
        // async-split: issue next tile's global loads now, consume next iter
        if (j0 + 64 <= jend) {
            sk0 = *(const bf16x8*)&kg[(size_t)(j0 + 64) * 1024];
            sk1 = *(const bf16x8*)&kg[(size_t)(j0 + 64) * 1024 + 32 * 1024];
            sv0 = *(const bf16x8*)&vg[j0 + 64];
            sv1 = *(const bf16x8*)&vg[32 * 1024 + j0 + 64];
        }

        if (j0 <= jmaxw) {
            // QK^T: s[kt] covers keys j0+kt*16+lr, q rows qbase+4lh+r
            f32x4 s[4] = {{0,0,0,0},{0,0,0,0},{0,0,0,0},{0,0,0,0}};
#pragma unroll
            for (int kt = 0; kt < 4; ++kt) {
                const int row = kt * 16 + lr;
                const int rswz = ((row & 7) << 4);
#pragma unroll
                for (int ks = 0; ks < 2; ++ks) {
                    bf16x8 kf = *(const bf16x8*)(kbase + row * 128 + ((ks * 64 + lh * 16) ^ rswz));
                    s[kt] = MFMA16(qf[ks], kf, s[kt]);
                }
            }
            if (j0 + 63 > qbase) {  // diagonal tile (wave-uniform): mask
#pragma unroll
                for (int kt = 0; kt < 4; ++kt)
#pragma unroll
                    for (int r = 0; r < 4; ++r)
                        s[kt][r] = ((j0 + kt * 16 + lr) <= (qbase + lh * 4 + r)) ? s[kt][r] : -1e9f;
            }
            // online softmax: row q = qbase+4lh+r lives in 16-lane groups
#pragma unroll
            for (int r = 0; r < 4; ++r) {
                float pm = fmaxf(fmaxf(s[0][r], s[1][r]), fmaxf(s[2][r], s[3][r]));
                pm = fmaxf(pm, __shfl_xor(pm, 1, 16));
                pm = fmaxf(pm, __shfl_xor(pm, 2, 16));
                pm = fmaxf(pm, __shfl_xor(pm, 4, 16));
                pm = fmaxf(pm, __shfl_xor(pm, 8, 16));
                const float mn = fmaxf(m[r], pm);
                const float corr = __expf(m[r] - mn);
                m[r] = mn;
                float p0 = __expf(s[0][r] - mn);
                float p1 = __expf(s[1][r] - mn);
                float p2 = __expf(s[2][r] - mn);
                float p3 = __expf(s[3][r] - mn);
                s[0][r] = p0; s[1][r] = p1; s[2][r] = p2; s[3][r] = p3;
                float ps = (p0 + p1) + (p2 + p3);
                ps += __shfl_xor(ps, 1, 16);
                ps += __shfl_xor(ps, 2, 16);
                ps += __shfl_xor(ps, 4, 16);
                ps += __shfl_xor(ps, 8, 16);
                ls[r] = ls[r] * corr + ps;
                oacc[0][r] *= corr; oacc[1][r] *= corr;
                oacc[2][r] *= corr; oacc[3][r] *= corr;
            }
            // P -> wave-private LDS (swizzled), then A-frag reads
            char* const pb = (char*)p_lds[w];
#pragma unroll
            for (int r = 0; r < 4; ++r) {
                const int qrow = lh * 4 + r;
                const int qswz = ((qrow & 7) << 4);
#pragma unroll
                for (int kt = 0; kt < 4; ++kt)
                    *(ushort_t*)(pb + qrow * 128 + ((kt * 32 + lr * 2) ^ qswz)) = f2bf(s[kt][r]);
            }
            const int pswz = ((lr & 7) << 4);
            bf16x8 pa0 = *(const bf16x8*)(pb + lr * 128 + ((lh * 16) ^ pswz));
            bf16x8 pa1 = *(const bf16x8*)(pb + lr * 128 + ((64 + lh * 16) ^ pswz));
#pragma unroll
            for (int dt = 0; dt < 4; ++dt) {
                const int vrow = dt * 16 + lr;
                const int vswz = ((vrow & 7) << 4);
                bf16x8 vf0 = *(const bf16x8*)(vbase + vrow * 128 + ((lh * 16) ^ vswz));
                oacc[dt] = MFMA16(pa0, vf0, oacc[dt]);
                bf16x8 vf1 = *(const bf16x8*)(vbase + vrow * 128 + ((64 + lh * 16) ^ vswz));
                oacc[dt] = MFMA16(pa1, vf1, oacc[dt]);
            }
        }
    }

    float inv[4];
#pragma unroll
    for (int r = 0; r < 4; ++r) inv[r] = 1.f / ls[r];
#pragma unroll
    for (int dt = 0; dt < 4; ++dt)
#pragma unroll
        for (int r = 0; r < 4; ++r) {
            const int row = qbase + lh * 4 + r;
            o[headoff + (size_t)row * 1024 + dt * 16 + lr] = f2bf(oacc[dt][r] * inv[r]);
        }
}

// ---------------------------------------------------------------------------
// fused residual + LayerNorm: x = LN(t + x); writes f32 x and bf16 xb
// ---------------------------------------------------------------------------
__global__ __launch_bounds__(256) void add_ln(const float* __restrict__ t,
                                              float* __restrict__ x,
                                              const float* __restrict__ g,
                                              const float* __restrict__ bb,
                                              ushort_t* __restrict__ xb) {
    const int row = blockIdx.x, tid = threadIdx.x;
    const int lane = tid & 63, w = tid >> 6;
    const size_t base = (size_t)row * 1024;
    float4 tv = ((const float4*)(t + base))[tid];
    float4 xv = ((const float4*)(x + base))[tid];
    float v0 = tv.x + xv.x, v1 = tv.y + xv.y, v2 = tv.z + xv.z, v3 = tv.w + xv.w;
    float s = v0 + v1 + v2 + v3;
    float sq = v0 * v0 + v1 * v1 + v2 * v2 + v3 * v3;
#pragma unroll
    for (int off = 32; off >= 1; off >>= 1) {
        s += __shfl_xor(s, off);
        sq += __shfl_xor(sq, off);
    }
    __shared__ float red[8];
    if (lane == 0) { red[w] = s; red[4 + w] = sq; }
    __syncthreads();
    s = red[0] + red[1] + red[2] + red[3];
    sq = red[4] + red[5] + red[6] + red[7];
    const float mu = s * (1.f / 1024.f);
    const float var = sq * (1.f / 1024.f) - mu * mu;
    const float rs = rsqrtf(var + 1e-6f);
    float4 gv = ((const float4*)g)[tid];
    float4 bv = ((const float4*)bb)[tid];
    float y0 = (v0 - mu) * rs * gv.x + bv.x;
    float y1 = (v1 - mu) * rs * gv.y + bv.y;
    float y2 = (v2 - mu) * rs * gv.z + bv.z;
    float y3 = (v3 - mu) * rs * gv.w + bv.w;
    float4 yo; yo.x = y0; yo.y = y1; yo.z = y2; yo.w = y3;
    ((float4*)(x + base))[tid] = yo;
    ushort4 hh;
    hh.x = f2bf(y0); hh.y = f2bf(y1); hh.z = f2bf(y2); hh.w = f2bf(y3);
    ((ushort4*)(xb + base))[tid] = hh;
}

// ---------------------------------------------------------------------------
extern "C" void kernel_launch(void* const* d_in, const int* in_sizes, int n_in,
                              void* d_out, int out_size, void* d_ws, size_t ws_size,
                              hipStream_t stream) {
    (void)in_sizes; (void)n_in; (void)out_size; (void)ws_size;
    const int B = 8, S = 1024, D = 1024, DFF = 4096, L = 2;
    const int M = B * S;  // 8192

    const float* x_in = (const float*)d_in[0];
    const float* Wq = (const float*)d_in[2];
    const float* bq = (const float*)d_in[3];
    const float* Wk = (const float*)d_in[4];
    const float* bk = (const float*)d_in[5];
    const float* Wv = (const float*)d_in[6];
    const float* bv = (const float*)d_in[7];
    const float* Wo = (const float*)d_in[8];
    const float* bo = (const float*)d_in[9];
    const float* W1 = (const float*)d_in[10];
    const float* b1 = (const float*)d_in[11];
    const float* W2 = (const float*)d_in[12];
    const float* b2 = (const float*)d_in[13];
    const float* ln1g = (const float*)d_in[14];
    const float* ln1b = (const float*)d_in[15];
    const float* ln2g = (const float*)d_in[16];
    const float* ln2b = (const float*)d_in[17];

    float* x = (float*)d_out;  // running f32 activation buffer
    char* ws = (char*)d_ws;
    const size_t MB = 1024 * 1024;
    ushort_t* wqkvT = (ushort_t*)(ws + 0 * MB);   // 12MB (2 layers x 3072x1024)
    ushort_t* woT = (ushort_t*)(ws + 12 * MB);    // 4MB
    ushort_t* w1T = (ushort_t*)(ws + 16 * MB);    // 16MB
    ushort_t* w2T = (ushort_t*)(ws + 32 * MB);    // 16MB
    ushort_t* xb  = (ushort_t*)(ws + 48 * MB);    // 16MB
    ushort_t* qb  = (ushort_t*)(ws + 64 * MB);    // 16MB
    ushort_t* kb  = (ushort_t*)(ws + 80 * MB);    // 16MB
    ushort_t* vtb = (ushort_t*)(ws + 96 * MB);    // 16MB  (B,H,DH,S)
    ushort_t* ob  = (ushort_t*)(ws + 112 * MB);   // 16MB
    ushort_t* hb  = (ushort_t*)(ws + 64 * MB);    // 64MB, reuses q/k/vt/o region
    float* t      = (float*)(ws + 128 * MB);      // 32MB f32

    init_x<<<M * D / 4 / 256, 256, 0, stream>>>(x_in, x, xb, M * D / 4);

    dim3 tb(32, 8);
    for (int l = 0; l < L; ++l) {
        const size_t wOff = (size_t)l * D * D;
        const size_t qkvOff = (size_t)l * 3 * D * D;
        transpose_convert<<<dim3(D / 32, D / 32), tb, 0, stream>>>(Wq + wOff, wqkvT + qkvOff, D, D);
        transpose_convert<<<dim3(D / 32, D / 32), tb, 0, stream>>>(Wk + wOff, wqkvT + qkvOff + (size_t)D * D, D, D);
        transpose_convert<<<dim3(D / 32, D / 32), tb, 0, stream>>>(Wv + wOff, wqkvT + qkvOff + 2 * (size_t)D * D, D, D);
        transpose_convert<<<dim3(D / 32, D / 32), tb, 0, stream>>>(Wo + wOff, woT + wOff, D, D);
        transpose_convert<<<dim3(DFF / 32, D / 32), tb, 0, stream>>>(W1 + (size_t)l * D * DFF, w1T + (size_t)l * D * DFF, D, DFF);
        transpose_convert<<<dim3(D / 32, DFF / 32), tb, 0, stream>>>(W2 + (size_t)l * DFF * D, w2T + (size_t)l * DFF * D, DFF, D);
    }

    for (int l = 0; l < L; ++l) {
        const size_t wOff = (size_t)l * D * D;
        const size_t bOff = (size_t)l * D;
        // QKV: M=8192, N=3072, K=1024; 256x256 tiles -> 32x12 = 384 blocks
        gemm8p<256, 2, 0><<<dim3(384), 512, 0, stream>>>(
            xb, wqkvT + (size_t)l * 3 * D * D, nullptr, nullptr, M, 3 * D, D, 12,
            qb, kb, vtb, bq + bOff, bk + bOff, bv + bOff);
        attn_kernel<<<dim3(B * 16, S / 64), 256, 0, stream>>>(qb, kb, vtb, ob);
        // Wo: N=1024; 128x256 tiles -> 64x4 = 256 blocks (fills all CUs)
        gemm8p<128, 0, 0><<<dim3(256), 512, 0, stream>>>(
            ob, woT + wOff, bo + bOff, t, M, D, D, 4,
            nullptr, nullptr, nullptr, nullptr, nullptr, nullptr);
        add_ln<<<M, 256, 0, stream>>>(t, x, ln1g + bOff, ln1b + bOff, xb);
        // FFN1: N=4096; 256x256 -> 32x16 = 512 blocks
        gemm8p<256, 1, 1><<<dim3(512), 512, 0, stream>>>(
            xb, w1T + (size_t)l * D * DFF, b1 + (size_t)l * DFF, hb, M, DFF, D, 16,
            nullptr, nullptr, nullptr, nullptr, nullptr, nullptr);
        // FFN2: N=1024, K=4096; 128x256 -> 256 blocks
        gemm8p<128, 0, 0><<<dim3(256), 512, 0, stream>>>(
            hb, w2T + (size_t)l * DFF * D, b2 + bOff, t, M, D, DFF, 4,
            nullptr, nullptr, nullptr, nullptr, nullptr, nullptr);
        add_ln<<<M, 256, 0, stream>>>(t, x, ln2g + bOff, ln2b + bOff, xb);
    }
}

// Round 5
// 735.318 us; speedup vs baseline: 1.6163x; 1.0451x over previous
//
#include <hip/hip_runtime.h>

typedef __attribute__((ext_vector_type(8))) short bf16x8;
typedef __attribute__((ext_vector_type(4))) float f32x4;
typedef unsigned short ushort_t;
typedef unsigned int uint32;

#define DEV __device__ __forceinline__

// round-to-nearest-even f32 -> bf16 (bits)
DEV ushort_t f2bf(float f) {
    uint32 u = __float_as_uint(f);
    uint32 r = (u + 0x7FFFu + ((u >> 16) & 1u)) >> 16;
    return (ushort_t)r;
}
DEV float bf2f(ushort_t h) { return __uint_as_float(((uint32)h) << 16); }

#define MFMA16(a, b, c) __builtin_amdgcn_mfma_f32_16x16x32_bf16((a), (b), (c), 0, 0, 0)

DEV void gload_lds16(const void* g, void* l) {
    __builtin_amdgcn_global_load_lds((const __attribute__((address_space(1))) void*)g,
                                     (__attribute__((address_space(3))) void*)l,
                                     16, 0, 0);
}

// ---------------------------------------------------------------------------
// init: copy f32 x -> d_out (running x buffer) and bf16 xb
// ---------------------------------------------------------------------------
__global__ __launch_bounds__(256) void init_x(const float* __restrict__ xin,
                                              float* __restrict__ x,
                                              ushort_t* __restrict__ xb, int n4) {
    int i = blockIdx.x * 256 + threadIdx.x;
    if (i >= n4) return;
    float4 v = ((const float4*)xin)[i];
    ((float4*)x)[i] = v;
    ushort4 h;
    h.x = f2bf(v.x); h.y = f2bf(v.y); h.z = f2bf(v.z); h.w = f2bf(v.w);
    ((ushort4*)xb)[i] = h;
}

// ---------------------------------------------------------------------------
// all weight transposes in ONE launch: src (K x N f32) -> dst (N x K bf16).
// grid.x = 12288 tiles (q,k,v,o: 4x1024 | W1: 4096 | W2: 4096), grid.y = layer
// ---------------------------------------------------------------------------
__global__ __launch_bounds__(256) void transpose_all(const float* __restrict__ Wq,
                                                     const float* __restrict__ Wk,
                                                     const float* __restrict__ Wv,
                                                     const float* __restrict__ Wo,
                                                     const float* __restrict__ W1,
                                                     const float* __restrict__ W2,
                                                     ushort_t* __restrict__ wqkvT,
                                                     ushort_t* __restrict__ woT,
                                                     ushort_t* __restrict__ w1T,
                                                     ushort_t* __restrict__ w2T) {
    const int l = blockIdx.y;
    const int t = blockIdx.x;
    const float* src;
    ushort_t* dst;
    int K, N, ktile, ntile;
    if (t < 4096) {
        const int which = t >> 10, tile = t & 1023;
        K = 1024; N = 1024; ktile = tile >> 5; ntile = tile & 31;
        const size_t o1 = (size_t)l * 1048576;
        if (which == 0)      { src = Wq + o1; dst = wqkvT + (size_t)l * 3145728; }
        else if (which == 1) { src = Wk + o1; dst = wqkvT + (size_t)l * 3145728 + 1048576; }
        else if (which == 2) { src = Wv + o1; dst = wqkvT + (size_t)l * 3145728 + 2097152; }
        else                 { src = Wo + o1; dst = woT + o1; }
    } else if (t < 8192) {
        const int tile = t - 4096;
        K = 1024; N = 4096; ktile = tile >> 7; ntile = tile & 127;
        src = W1 + (size_t)l * 4194304; dst = w1T + (size_t)l * 4194304;
    } else {
        const int tile = t - 8192;
        K = 4096; N = 1024; ktile = tile >> 5; ntile = tile & 31;
        src = W2 + (size_t)l * 4194304; dst = w2T + (size_t)l * 4194304;
    }
    __shared__ float tilebuf[32][33];
    const int tx = threadIdx.x, ty = threadIdx.y;  // (32,8)
    const int nt = ntile * 32, kt = ktile * 32;
#pragma unroll
    for (int j = 0; j < 4; ++j)
        tilebuf[ty + j * 8][tx] = src[(size_t)(kt + ty + j * 8) * N + nt + tx];
    __syncthreads();
#pragma unroll
    for (int j = 0; j < 4; ++j)
        dst[(size_t)(nt + ty + j * 8) * K + kt + tx] = f2bf(tilebuf[tx][ty + j * 8]);
}

// ---------------------------------------------------------------------------
// 8-phase GEMM (m201 template, plain HIP): C[M,N] = A[M,K] @ BT[N,K]^T + bias
// BM x 256 tile, BK=64, 8 waves (2M x 4N), per-wave (BM/2) x 64 C.
// Double-buffered LDS, XOR-swizzled via pre-swizzled global source.
// Counted vmcnt(4) once per K-tile; raw s_barrier; setprio around MFMA.
// MODE: 1 = bf16 out (+RELU), 2 = fused QKV split (q scaled 1/8; v -> vt).
// ---------------------------------------------------------------------------
template <int BM, int MODE, int RELU>
__global__ __launch_bounds__(512, 2) void gemm8p(const ushort_t* __restrict__ A,
                                                 const ushort_t* __restrict__ BT,
                                                 const float* __restrict__ bias,
                                                 void* __restrict__ Cout,
                                                 int M, int N, int K, int gx,
                                                 ushort_t* __restrict__ qout,
                                                 ushort_t* __restrict__ kout,
                                                 ushort_t* __restrict__ vtout,
                                                 const float* __restrict__ bq,
                                                 const float* __restrict__ bk,
                                                 const float* __restrict__ bv) {
    constexpr int AH = BM / 128;    // # of 128-row A halves
    constexpr int MREP = BM / 32;   // M frags per wave
    constexpr int MPP = MREP / 4;   // M frags per phase
    __shared__ ushort_t lds[2][(BM + 256) * 64];

    // XCD-aware bijective swizzle (m204)
    const int nwg = gridDim.x;
    const int q8 = nwg >> 3, r8 = nwg & 7;
    const int xcd = blockIdx.x & 7, idx = blockIdx.x >> 3;
    const int swz = (xcd < r8 ? xcd * (q8 + 1) : r8 * (q8 + 1) + (xcd - r8) * q8) + idx;
    const int bxi = swz % gx, byi = swz / gx;

    const int tid = threadIdx.x;
    const int w = tid >> 6, lane = tid & 63;
    const int wr = w >> 2, wc = w & 3;
    const int lr = lane & 15, lh = lane >> 4;
    const int row0 = byi * BM, col0 = bxi * 256;

    f32x4 acc[MREP][4] = {};

    const ushort_t* __restrict__ Ab = A + (size_t)row0 * K;
    const ushort_t* __restrict__ Bb = BT + (size_t)col0 * K;
    const int nt = K >> 6;

    const int r8l = lane >> 3;            // 0..7 row within 8-row block
    const int cu = (lane & 7) ^ r8l;      // swizzled col unit (16B)

    auto stage_half = [&](const ushort_t* src, ushort_t* lbase) {
#pragma unroll
        for (int i = 0; i < 2; ++i) {
            const int rowi = (w * 2 + i) * 8 + r8l;
            gload_lds16(src + (size_t)rowi * K + cu * 8, lbase + (w * 2 + i) * 512 + lane * 8);
        }
    };
    auto Ahalf = [&](int buf, int h) -> ushort_t* { return &lds[buf][h * 8192]; };
    auto Bhalf = [&](int buf, int h) -> ushort_t* { return &lds[buf][BM * 64 + h * 8192]; };
    auto stA = [&](int kt, int h, int buf) {
        stage_half(Ab + (size_t)h * 128 * K + (size_t)kt * 64, Ahalf(buf, h));
    };
    auto stB = [&](int kt, int h, int buf) {
        stage_half(Bb + (size_t)h * 128 * K + (size_t)kt * 64, Bhalf(buf, h));
    };

    // prologue: tile 0 (A+B) + B halves of tile 1; vmcnt(4) completes tile 0
    stB(0, 0, 0); stB(0, 1, 0);
    stA(0, 0, 0); if (AH == 2) stA(0, 1, 0);
    stB(1, 0, 1); stB(1, 1, 1);
    asm volatile("s_waitcnt vmcnt(4)" ::: "memory");
    __builtin_amdgcn_sched_barrier(0);
    __builtin_amdgcn_s_barrier();

    for (int t = 0; t < nt; ++t) {
        const int cb = t & 1, nb = cb ^ 1;
        bf16x8 bfrag[4][2];
#pragma unroll
        for (int p = 0; p < 4; ++p) {
            // --- ds-reads for this phase ---
            if (p == 0) {
#pragma unroll
                for (int ni = 0; ni < 4; ++ni) {
                    const int br = wc * 64 + ni * 16 + lr;
                    const ushort_t* bh = Bhalf(cb, br >> 7);
                    const int rr = br & 127;
#pragma unroll
                    for (int ks = 0; ks < 2; ++ks)
                        bfrag[ni][ks] = *(const bf16x8*)&bh[rr * 64 + (((ks * 4 + lh) ^ (rr & 7)) * 8)];
                }
            }
            bf16x8 af[MPP][2];
#pragma unroll
            for (int mm = 0; mm < MPP; ++mm) {
                const int fr = wr * (BM / 2) + (p * MPP + mm) * 16 + lr;
                const ushort_t* ah = Ahalf(cb, fr >> 7);
                const int rr = fr & 127;
#pragma unroll
                for (int ks = 0; ks < 2; ++ks)
                    af[mm][ks] = *(const bf16x8*)&ah[rr * 64 + (((ks * 4 + lh) ^ (rr & 7)) * 8)];
            }
            // --- stage one half-tile ---
            if (p == 0) { if (t + 1 < nt) stA(t + 1, 0, nb); }
            else if (p == 1) { if (AH == 2 && t + 1 < nt) stA(t + 1, 1, nb); }
            else if (p == 2) { if (t + 2 < nt) stB(t + 2, 0, cb); }
            else {
                if (t + 2 < nt) {
                    stB(t + 2, 1, cb);
                    asm volatile("s_waitcnt vmcnt(4)" ::: "memory");
                } else if (t + 1 < nt) {
                    asm volatile("s_waitcnt vmcnt(0)" ::: "memory");
                }
            }
            __builtin_amdgcn_sched_barrier(0);
            __builtin_amdgcn_s_barrier();
            asm volatile("s_waitcnt lgkmcnt(0)" ::: "memory");
            __builtin_amdgcn_sched_barrier(0);
            __builtin_amdgcn_s_setprio(1);
#pragma unroll
            for (int mm = 0; mm < MPP; ++mm)
#pragma unroll
                for (int ni = 0; ni < 4; ++ni)
#pragma unroll
                    for (int ks = 0; ks < 2; ++ks)
                        acc[p * MPP + mm][ni] = MFMA16(af[mm][ks], bfrag[ni][ks], acc[p * MPP + mm][ni]);
            __builtin_amdgcn_s_setprio(0);
            __builtin_amdgcn_sched_barrier(0);
            __builtin_amdgcn_s_barrier();
        }
    }
    (void)M;

    // epilogue
#pragma unroll
    for (int mi = 0; mi < MREP; ++mi) {
#pragma unroll
        for (int ni = 0; ni < 4; ++ni) {
            const int col = col0 + wc * 64 + ni * 16 + lr;
            const int rowb = row0 + wr * (BM / 2) + mi * 16 + lh * 4;
            if (MODE == 2) {
                if (col < 1024) {  // q, pre-scaled by 1/8 (exact in bf16)
                    const float bvv = bq[col];
#pragma unroll
                    for (int r = 0; r < 4; ++r)
                        qout[(size_t)(rowb + r) * 1024 + col] = f2bf((acc[mi][ni][r] + bvv) * 0.125f);
                } else if (col < 2048) {
                    const int c = col - 1024;
                    const float bvv = bk[c];
#pragma unroll
                    for (int r = 0; r < 4; ++r)
                        kout[(size_t)(rowb + r) * 1024 + c] = f2bf(acc[mi][ni][r] + bvv);
                } else {
                    const int d = col - 2048;
                    const int h = d >> 6, dd = d & 63;
                    const int b = rowb >> 10, s = rowb & 1023;
                    const float bvv = bv[d];
                    ushort4 h4;
                    h4.x = f2bf(acc[mi][ni][0] + bvv);
                    h4.y = f2bf(acc[mi][ni][1] + bvv);
                    h4.z = f2bf(acc[mi][ni][2] + bvv);
                    h4.w = f2bf(acc[mi][ni][3] + bvv);
                    *(ushort4*)&vtout[(((size_t)(b * 16 + h) * 64 + dd) << 10) + s] = h4;
                }
            } else {
                const float bvv = bias[col];
#pragma unroll
                for (int r = 0; r < 4; ++r) {
                    float val = acc[mi][ni][r] + bvv;
                    if (RELU) val = fmaxf(val, 0.f);
                    ((ushort_t*)Cout)[(size_t)(rowb + r) * N + col] = f2bf(val);
                }
            }
        }
    }
}

// ---------------------------------------------------------------------------
// fused causal flash attention. Grid: (bh=128, qt=16) so same-head blocks land
// on the same XCD (L2 locality for K/V). Block = 4 waves x 16 q rows = 64 rows.
// K and V^T staged in LDS per 64-key tile (XOR-swizzled), async-split staging.
// q is pre-scaled by 1/8.
// ---------------------------------------------------------------------------
__global__ __launch_bounds__(256) void attn_kernel(const ushort_t* __restrict__ q,
                                                   const ushort_t* __restrict__ k,
                                                   const ushort_t* __restrict__ vt,
                                                   ushort_t* __restrict__ o) {
    __shared__ ushort_t ktile[64 * 64];     // 8KB, swizzled rows of 128B
    __shared__ ushort_t vtile[64 * 64];     // 8KB, V^T (dh x key), swizzled
    __shared__ ushort_t p_lds[4][16 * 64];  // 8KB, per-wave P, swizzled

    const int bh = blockIdx.x;
    const int b = bh >> 4, h = bh & 15;
    const int qt = blockIdx.y;
    const int tid = threadIdx.x, w = tid >> 6, lane = tid & 63;
    const int lr = lane & 15, lh = lane >> 4;
    const int qbase = qt * 64 + w * 16;
    const size_t headoff = (size_t)b * 1024 * 1024 + h * 64;
    const size_t vhead = (size_t)(b * 16 + h) << 16;  // *64*1024

    bf16x8 qf[2];
#pragma unroll
    for (int ks = 0; ks < 2; ++ks)
        qf[ks] = *(const bf16x8*)&q[headoff + (size_t)(qbase + lr) * 1024 + ks * 32 + lh * 8];

    f32x4 oacc[4] = {};
    float m[4] = {-INFINITY, -INFINITY, -INFINITY, -INFINITY};
    float ls[4] = {0.f, 0.f, 0.f, 0.f};

    // staging geometry: 256 threads, rows of 128B (8 lanes x 16B), 2 passes
    const int srow = tid >> 3;            // 0..31
    const int scolb = (tid & 7) * 16;     // byte col within 128B row
    const int swz0 = ((srow & 7) << 4);   // row XOR mask (same for srow, srow+32)
    char* const kbase = (char*)ktile;
    char* const vbase = (char*)vtile;
    char* const kw0 = kbase + srow * 128 + (scolb ^ swz0);
    char* const kw1 = kbase + (srow + 32) * 128 + (scolb ^ swz0);
    char* const vw0 = vbase + srow * 128 + (scolb ^ swz0);
    char* const vw1 = vbase + (srow + 32) * 128 + (scolb ^ swz0);
    const ushort_t* kg = k + headoff + (size_t)srow * 1024 + (tid & 7) * 8;
    const ushort_t* vg = vt + vhead + (size_t)srow * 1024 + (tid & 7) * 8;

    const int jmaxw = qbase + 15;       // per-wave causal bound
    const int jend = qt * 64 + 63;      // block bound

    bf16x8 sk0 = *(const bf16x8*)&kg[0];
    bf16x8 sk1 = *(const bf16x8*)&kg[32 * 1024];
    bf16x8 sv0 = *(const bf16x8*)&vg[0];
    bf16x8 sv1 = *(const bf16x8*)&vg[32 * 1024];

    for (int j0 = 0; j0 <= jend; j0 += 64) {
        __syncthreads();  // LDS safe to overwrite
        *(bf16x8*)kw0 = sk0;
        *(bf16x8*)kw1 = sk1;
        *(bf16x8*)vw0 = sv0;
        *(bf16x8*)vw1 = sv1;
        __syncthreads();
        // async-split: issue next tile's global loads now, consume next iter
        if (j0 + 64 <= jend) {
            sk0 = *(const bf16x8*)&kg[(size_t)(j0 + 64) * 1024];
            sk1 = *(const bf16x8*)&kg[(size_t)(j0 + 64) * 1024 + 32 * 1024];
            sv0 = *(const bf16x8*)&vg[j0 + 64];
            sv1 = *(const bf16x8*)&vg[32 * 1024 + j0 + 64];
        }

        if (j0 <= jmaxw) {
            // QK^T: s[kt] covers keys j0+kt*16+lr, q rows qbase+4lh+r
            f32x4 s[4] = {{0,0,0,0},{0,0,0,0},{0,0,0,0},{0,0,0,0}};
#pragma unroll
            for (int kt = 0; kt < 4; ++kt) {
                const int row = kt * 16 + lr;
                const int rswz = ((row & 7) << 4);
#pragma unroll
                for (int ks = 0; ks < 2; ++ks) {
                    bf16x8 kf = *(const bf16x8*)(kbase + row * 128 + ((ks * 64 + lh * 16) ^ rswz));
                    s[kt] = MFMA16(qf[ks], kf, s[kt]);
                }
            }
            if (j0 + 63 > qbase) {  // diagonal tile (wave-uniform): mask
#pragma unroll
                for (int kt = 0; kt < 4; ++kt)
#pragma unroll
                    for (int r = 0; r < 4; ++r)
                        s[kt][r] = ((j0 + kt * 16 + lr) <= (qbase + lh * 4 + r)) ? s[kt][r] : -1e9f;
            }
            // online softmax: row q = qbase+4lh+r lives in 16-lane groups
#pragma unroll
            for (int r = 0; r < 4; ++r) {
                float pm = fmaxf(fmaxf(s[0][r], s[1][r]), fmaxf(s[2][r], s[3][r]));
                pm = fmaxf(pm, __shfl_xor(pm, 1, 16));
                pm = fmaxf(pm, __shfl_xor(pm, 2, 16));
                pm = fmaxf(pm, __shfl_xor(pm, 4, 16));
                pm = fmaxf(pm, __shfl_xor(pm, 8, 16));
                const float mn = fmaxf(m[r], pm);
                const float corr = __expf(m[r] - mn);
                m[r] = mn;
                float p0 = __expf(s[0][r] - mn);
                float p1 = __expf(s[1][r] - mn);
                float p2 = __expf(s[2][r] - mn);
                float p3 = __expf(s[3][r] - mn);
                s[0][r] = p0; s[1][r] = p1; s[2][r] = p2; s[3][r] = p3;
                float ps = (p0 + p1) + (p2 + p3);
                ps += __shfl_xor(ps, 1, 16);
                ps += __shfl_xor(ps, 2, 16);
                ps += __shfl_xor(ps, 4, 16);
                ps += __shfl_xor(ps, 8, 16);
                ls[r] = ls[r] * corr + ps;
                oacc[0][r] *= corr; oacc[1][r] *= corr;
                oacc[2][r] *= corr; oacc[3][r] *= corr;
            }
            // P -> wave-private LDS (swizzled), then A-frag reads
            char* const pb = (char*)p_lds[w];
#pragma unroll
            for (int r = 0; r < 4; ++r) {
                const int qrow = lh * 4 + r;
                const int qswz = ((qrow & 7) << 4);
#pragma unroll
                for (int kt = 0; kt < 4; ++kt)
                    *(ushort_t*)(pb + qrow * 128 + ((kt * 32 + lr * 2) ^ qswz)) = f2bf(s[kt][r]);
            }
            const int pswz = ((lr & 7) << 4);
            bf16x8 pa0 = *(const bf16x8*)(pb + lr * 128 + ((lh * 16) ^ pswz));
            bf16x8 pa1 = *(const bf16x8*)(pb + lr * 128 + ((64 + lh * 16) ^ pswz));
#pragma unroll
            for (int dt = 0; dt < 4; ++dt) {
                const int vrow = dt * 16 + lr;
                const int vswz = ((vrow & 7) << 4);
                bf16x8 vf0 = *(const bf16x8*)(vbase + vrow * 128 + ((lh * 16) ^ vswz));
                oacc[dt] = MFMA16(pa0, vf0, oacc[dt]);
                bf16x8 vf1 = *(const bf16x8*)(vbase + vrow * 128 + ((64 + lh * 16) ^ vswz));
                oacc[dt] = MFMA16(pa1, vf1, oacc[dt]);
            }
        }
    }

    float inv[4];
#pragma unroll
    for (int r = 0; r < 4; ++r) inv[r] = 1.f / ls[r];
#pragma unroll
    for (int dt = 0; dt < 4; ++dt)
#pragma unroll
        for (int r = 0; r < 4; ++r) {
            const int row = qbase + lh * 4 + r;
            o[headoff + (size_t)row * 1024 + dt * 16 + lr] = f2bf(oacc[dt][r] * inv[r]);
        }
}

// ---------------------------------------------------------------------------
// fused residual + LayerNorm: x = LN(t + x); t is bf16; writes f32 x, bf16 xb
// ---------------------------------------------------------------------------
__global__ __launch_bounds__(256) void add_ln(const ushort_t* __restrict__ t,
                                              float* __restrict__ x,
                                              const float* __restrict__ g,
                                              const float* __restrict__ bb,
                                              ushort_t* __restrict__ xb) {
    const int row = blockIdx.x, tid = threadIdx.x;
    const int lane = tid & 63, w = tid >> 6;
    const size_t base = (size_t)row * 1024;
    ushort4 tv = ((const ushort4*)(t + base))[tid];
    float4 xv = ((const float4*)(x + base))[tid];
    float v0 = bf2f(tv.x) + xv.x, v1 = bf2f(tv.y) + xv.y;
    float v2 = bf2f(tv.z) + xv.z, v3 = bf2f(tv.w) + xv.w;
    float s = v0 + v1 + v2 + v3;
    float sq = v0 * v0 + v1 * v1 + v2 * v2 + v3 * v3;
#pragma unroll
    for (int off = 32; off >= 1; off >>= 1) {
        s += __shfl_xor(s, off);
        sq += __shfl_xor(sq, off);
    }
    __shared__ float red[8];
    if (lane == 0) { red[w] = s; red[4 + w] = sq; }
    __syncthreads();
    s = red[0] + red[1] + red[2] + red[3];
    sq = red[4] + red[5] + red[6] + red[7];
    const float mu = s * (1.f / 1024.f);
    const float var = sq * (1.f / 1024.f) - mu * mu;
    const float rs = rsqrtf(var + 1e-6f);
    float4 gv = ((const float4*)g)[tid];
    float4 bv = ((const float4*)bb)[tid];
    float y0 = (v0 - mu) * rs * gv.x + bv.x;
    float y1 = (v1 - mu) * rs * gv.y + bv.y;
    float y2 = (v2 - mu) * rs * gv.z + bv.z;
    float y3 = (v3 - mu) * rs * gv.w + bv.w;
    float4 yo; yo.x = y0; yo.y = y1; yo.z = y2; yo.w = y3;
    ((float4*)(x + base))[tid] = yo;
    ushort4 hh;
    hh.x = f2bf(y0); hh.y = f2bf(y1); hh.z = f2bf(y2); hh.w = f2bf(y3);
    ((ushort4*)(xb + base))[tid] = hh;
}

// ---------------------------------------------------------------------------
extern "C" void kernel_launch(void* const* d_in, const int* in_sizes, int n_in,
                              void* d_out, int out_size, void* d_ws, size_t ws_size,
                              hipStream_t stream) {
    (void)in_sizes; (void)n_in; (void)out_size; (void)ws_size;
    const int B = 8, S = 1024, D = 1024, DFF = 4096, L = 2;
    const int M = B * S;  // 8192

    const float* x_in = (const float*)d_in[0];
    const float* Wq = (const float*)d_in[2];
    const float* bq = (const float*)d_in[3];
    const float* Wk = (const float*)d_in[4];
    const float* bk = (const float*)d_in[5];
    const float* Wv = (const float*)d_in[6];
    const float* bv = (const float*)d_in[7];
    const float* Wo = (const float*)d_in[8];
    const float* bo = (const float*)d_in[9];
    const float* W1 = (const float*)d_in[10];
    const float* b1 = (const float*)d_in[11];
    const float* W2 = (const float*)d_in[12];
    const float* b2 = (const float*)d_in[13];
    const float* ln1g = (const float*)d_in[14];
    const float* ln1b = (const float*)d_in[15];
    const float* ln2g = (const float*)d_in[16];
    const float* ln2b = (const float*)d_in[17];

    float* x = (float*)d_out;  // running f32 activation buffer
    char* ws = (char*)d_ws;
    const size_t MB = 1024 * 1024;
    ushort_t* wqkvT = (ushort_t*)(ws + 0 * MB);   // 12MB (2 layers x 3072x1024)
    ushort_t* woT = (ushort_t*)(ws + 12 * MB);    // 4MB
    ushort_t* w1T = (ushort_t*)(ws + 16 * MB);    // 16MB
    ushort_t* w2T = (ushort_t*)(ws + 32 * MB);    // 16MB
    ushort_t* xb  = (ushort_t*)(ws + 48 * MB);    // 16MB
    ushort_t* qb  = (ushort_t*)(ws + 64 * MB);    // 16MB
    ushort_t* kb  = (ushort_t*)(ws + 80 * MB);    // 16MB
    ushort_t* vtb = (ushort_t*)(ws + 96 * MB);    // 16MB  (B,H,DH,S)
    ushort_t* ob  = (ushort_t*)(ws + 112 * MB);   // 16MB
    ushort_t* hb  = (ushort_t*)(ws + 64 * MB);    // 64MB, reuses q/k/vt/o region
    ushort_t* tb  = (ushort_t*)(ws + 128 * MB);   // 16MB bf16 pre-LN summand

    init_x<<<M * D / 4 / 256, 256, 0, stream>>>(x_in, x, xb, M * D / 4);
    transpose_all<<<dim3(12288, L), dim3(32, 8), 0, stream>>>(
        Wq, Wk, Wv, Wo, W1, W2, wqkvT, woT, w1T, w2T);

    for (int l = 0; l < L; ++l) {
        const size_t wOff = (size_t)l * D * D;
        const size_t bOff = (size_t)l * D;
        // QKV: M=8192, N=3072, K=1024; 128x256 tiles -> 64x12 = 768 blocks (3/CU)
        gemm8p<128, 2, 0><<<dim3(768), 512, 0, stream>>>(
            xb, wqkvT + (size_t)l * 3 * D * D, nullptr, nullptr, M, 3 * D, D, 12,
            qb, kb, vtb, bq + bOff, bk + bOff, bv + bOff);
        attn_kernel<<<dim3(B * 16, S / 64), 256, 0, stream>>>(qb, kb, vtb, ob);
        // Wo: N=1024; 128x256 tiles -> 64x4 = 256 blocks; bf16 out -> tb
        gemm8p<128, 1, 0><<<dim3(256), 512, 0, stream>>>(
            ob, woT + wOff, bo + bOff, tb, M, D, D, 4,
            nullptr, nullptr, nullptr, nullptr, nullptr, nullptr);
        add_ln<<<M, 256, 0, stream>>>(tb, x, ln1g + bOff, ln1b + bOff, xb);
        // FFN1: N=4096; 256x256 -> 32x16 = 512 blocks (2/CU)
        gemm8p<256, 1, 1><<<dim3(512), 512, 0, stream>>>(
            xb, w1T + (size_t)l * D * DFF, b1 + (size_t)l * DFF, hb, M, DFF, D, 16,
            nullptr, nullptr, nullptr, nullptr, nullptr, nullptr);
        // FFN2: N=1024, K=4096; 128x256 -> 256 blocks; bf16 out -> tb
        gemm8p<128, 1, 0><<<dim3(256), 512, 0, stream>>>(
            hb, w2T + (size_t)l * DFF * D, b2 + bOff, tb, M, D, DFF, 4,
            nullptr, nullptr, nullptr, nullptr, nullptr, nullptr);
        add_ln<<<M, 256, 0, stream>>>(tb, x, ln2g + bOff, ln2b + bOff, xb);
    }
}

// Round 6
// 699.834 us; speedup vs baseline: 1.6982x; 1.0507x over previous
//
#include <hip/hip_runtime.h>

typedef __attribute__((ext_vector_type(8))) short bf16x8;
typedef __attribute__((ext_vector_type(4))) float f32x4;
typedef unsigned short ushort_t;
typedef unsigned int uint32;

#define DEV __device__ __forceinline__

// round-to-nearest-even f32 -> bf16 (bits)
DEV ushort_t f2bf(float f) {
    uint32 u = __float_as_uint(f);
    uint32 r = (u + 0x7FFFu + ((u >> 16) & 1u)) >> 16;
    return (ushort_t)r;
}
DEV float bf2f(ushort_t h) { return __uint_as_float(((uint32)h) << 16); }

#define MFMA16(a, b, c) __builtin_amdgcn_mfma_f32_16x16x32_bf16((a), (b), (c), 0, 0, 0)

DEV void gload_lds16(const void* g, void* l) {
    __builtin_amdgcn_global_load_lds((const __attribute__((address_space(1))) void*)g,
                                     (__attribute__((address_space(3))) void*)l,
                                     16, 0, 0);
}

// ---------------------------------------------------------------------------
// init: f32 x -> bf16 residual stream xr
// ---------------------------------------------------------------------------
__global__ __launch_bounds__(256) void init_x(const float* __restrict__ xin,
                                              ushort_t* __restrict__ xr, int n4) {
    int i = blockIdx.x * 256 + threadIdx.x;
    if (i >= n4) return;
    float4 v = ((const float4*)xin)[i];
    ushort4 h;
    h.x = f2bf(v.x); h.y = f2bf(v.y); h.z = f2bf(v.z); h.w = f2bf(v.w);
    ((ushort4*)xr)[i] = h;
}

// ---------------------------------------------------------------------------
// all weight transposes in ONE launch: src (K x N f32) -> dst (N x K bf16).
// grid.x = 12288 tiles (q,k,v,o: 4x1024 | W1: 4096 | W2: 4096), grid.y = layer
// ---------------------------------------------------------------------------
__global__ __launch_bounds__(256) void transpose_all(const float* __restrict__ Wq,
                                                     const float* __restrict__ Wk,
                                                     const float* __restrict__ Wv,
                                                     const float* __restrict__ Wo,
                                                     const float* __restrict__ W1,
                                                     const float* __restrict__ W2,
                                                     ushort_t* __restrict__ wqkvT,
                                                     ushort_t* __restrict__ woT,
                                                     ushort_t* __restrict__ w1T,
                                                     ushort_t* __restrict__ w2T) {
    const int l = blockIdx.y;
    const int t = blockIdx.x;
    const float* src;
    ushort_t* dst;
    int K, N, ktile, ntile;
    if (t < 4096) {
        const int which = t >> 10, tile = t & 1023;
        K = 1024; N = 1024; ktile = tile >> 5; ntile = tile & 31;
        const size_t o1 = (size_t)l * 1048576;
        if (which == 0)      { src = Wq + o1; dst = wqkvT + (size_t)l * 3145728; }
        else if (which == 1) { src = Wk + o1; dst = wqkvT + (size_t)l * 3145728 + 1048576; }
        else if (which == 2) { src = Wv + o1; dst = wqkvT + (size_t)l * 3145728 + 2097152; }
        else                 { src = Wo + o1; dst = woT + o1; }
    } else if (t < 8192) {
        const int tile = t - 4096;
        K = 1024; N = 4096; ktile = tile >> 7; ntile = tile & 127;
        src = W1 + (size_t)l * 4194304; dst = w1T + (size_t)l * 4194304;
    } else {
        const int tile = t - 8192;
        K = 4096; N = 1024; ktile = tile >> 5; ntile = tile & 31;
        src = W2 + (size_t)l * 4194304; dst = w2T + (size_t)l * 4194304;
    }
    __shared__ float tilebuf[32][33];
    const int tx = threadIdx.x, ty = threadIdx.y;  // (32,8)
    const int nt = ntile * 32, kt = ktile * 32;
#pragma unroll
    for (int j = 0; j < 4; ++j)
        tilebuf[ty + j * 8][tx] = src[(size_t)(kt + ty + j * 8) * N + nt + tx];
    __syncthreads();
#pragma unroll
    for (int j = 0; j < 4; ++j)
        dst[(size_t)(nt + ty + j * 8) * K + kt + tx] = f2bf(tilebuf[tx][ty + j * 8]);
}

// ---------------------------------------------------------------------------
// 8-phase GEMM (m201 template, plain HIP): C[M,N] = A[M,K] @ BT[N,K]^T + bias
// BM x 256 tile, BK=64, 8 waves (2M x 4N), per-wave (BM/2) x 64 C.
// Double-buffered LDS, XOR-swizzled via pre-swizzled global source.
// Counted vmcnt(4) once per K-tile; raw s_barrier; setprio around MFMA.
// MODE: 1 = bf16 out (+RELU), 2 = fused QKV split (q scaled 1/8; v -> vt via
//       per-wave LDS bounce so vt writes are full-line coalesced).
// ---------------------------------------------------------------------------
template <int BM, int MODE, int RELU>
__global__ __launch_bounds__(512, 2) void gemm8p(const ushort_t* __restrict__ A,
                                                 const ushort_t* __restrict__ BT,
                                                 const float* __restrict__ bias,
                                                 void* __restrict__ Cout,
                                                 int M, int N, int K, int gx,
                                                 ushort_t* __restrict__ qout,
                                                 ushort_t* __restrict__ kout,
                                                 ushort_t* __restrict__ vtout,
                                                 const float* __restrict__ bq,
                                                 const float* __restrict__ bk,
                                                 const float* __restrict__ bv) {
    constexpr int AH = BM / 128;    // # of 128-row A halves
    constexpr int MREP = BM / 32;   // M frags per wave
    constexpr int MPP = MREP / 4;   // M frags per phase
    __shared__ ushort_t lds[2][(BM + 256) * 64];

    // XCD-aware bijective swizzle (m204)
    const int nwg = gridDim.x;
    const int q8 = nwg >> 3, r8 = nwg & 7;
    const int xcd = blockIdx.x & 7, idx = blockIdx.x >> 3;
    const int swz = (xcd < r8 ? xcd * (q8 + 1) : r8 * (q8 + 1) + (xcd - r8) * q8) + idx;
    const int bxi = swz % gx, byi = swz / gx;

    const int tid = threadIdx.x;
    const int w = tid >> 6, lane = tid & 63;
    const int wr = w >> 2, wc = w & 3;
    const int lr = lane & 15, lh = lane >> 4;
    const int row0 = byi * BM, col0 = bxi * 256;

    f32x4 acc[MREP][4] = {};

    const ushort_t* __restrict__ Ab = A + (size_t)row0 * K;
    const ushort_t* __restrict__ Bb = BT + (size_t)col0 * K;
    const int nt = K >> 6;

    const int r8l = lane >> 3;            // 0..7 row within 8-row block
    const int cu = (lane & 7) ^ r8l;      // swizzled col unit (16B)

    auto stage_half = [&](const ushort_t* src, ushort_t* lbase) {
#pragma unroll
        for (int i = 0; i < 2; ++i) {
            const int rowi = (w * 2 + i) * 8 + r8l;
            gload_lds16(src + (size_t)rowi * K + cu * 8, lbase + (w * 2 + i) * 512 + lane * 8);
        }
    };
    auto Ahalf = [&](int buf, int h) -> ushort_t* { return &lds[buf][h * 8192]; };
    auto Bhalf = [&](int buf, int h) -> ushort_t* { return &lds[buf][BM * 64 + h * 8192]; };
    auto stA = [&](int kt, int h, int buf) {
        stage_half(Ab + (size_t)h * 128 * K + (size_t)kt * 64, Ahalf(buf, h));
    };
    auto stB = [&](int kt, int h, int buf) {
        stage_half(Bb + (size_t)h * 128 * K + (size_t)kt * 64, Bhalf(buf, h));
    };

    // prologue: tile 0 (A+B) + B halves of tile 1; vmcnt(4) completes tile 0
    stB(0, 0, 0); stB(0, 1, 0);
    stA(0, 0, 0); if (AH == 2) stA(0, 1, 0);
    stB(1, 0, 1); stB(1, 1, 1);
    asm volatile("s_waitcnt vmcnt(4)" ::: "memory");
    __builtin_amdgcn_sched_barrier(0);
    __builtin_amdgcn_s_barrier();

    for (int t = 0; t < nt; ++t) {
        const int cb = t & 1, nb = cb ^ 1;
        bf16x8 bfrag[4][2];
#pragma unroll
        for (int p = 0; p < 4; ++p) {
            // --- ds-reads for this phase ---
            if (p == 0) {
#pragma unroll
                for (int ni = 0; ni < 4; ++ni) {
                    const int br = wc * 64 + ni * 16 + lr;
                    const ushort_t* bh = Bhalf(cb, br >> 7);
                    const int rr = br & 127;
#pragma unroll
                    for (int ks = 0; ks < 2; ++ks)
                        bfrag[ni][ks] = *(const bf16x8*)&bh[rr * 64 + (((ks * 4 + lh) ^ (rr & 7)) * 8)];
                }
            }
            bf16x8 af[MPP][2];
#pragma unroll
            for (int mm = 0; mm < MPP; ++mm) {
                const int fr = wr * (BM / 2) + (p * MPP + mm) * 16 + lr;
                const ushort_t* ah = Ahalf(cb, fr >> 7);
                const int rr = fr & 127;
#pragma unroll
                for (int ks = 0; ks < 2; ++ks)
                    af[mm][ks] = *(const bf16x8*)&ah[rr * 64 + (((ks * 4 + lh) ^ (rr & 7)) * 8)];
            }
            // --- stage one half-tile ---
            if (p == 0) { if (t + 1 < nt) stA(t + 1, 0, nb); }
            else if (p == 1) { if (AH == 2 && t + 1 < nt) stA(t + 1, 1, nb); }
            else if (p == 2) { if (t + 2 < nt) stB(t + 2, 0, cb); }
            else {
                if (t + 2 < nt) {
                    stB(t + 2, 1, cb);
                    asm volatile("s_waitcnt vmcnt(4)" ::: "memory");
                } else if (t + 1 < nt) {
                    asm volatile("s_waitcnt vmcnt(0)" ::: "memory");
                }
            }
            __builtin_amdgcn_sched_barrier(0);
            __builtin_amdgcn_s_barrier();
            asm volatile("s_waitcnt lgkmcnt(0)" ::: "memory");
            __builtin_amdgcn_sched_barrier(0);
            __builtin_amdgcn_s_setprio(1);
#pragma unroll
            for (int mm = 0; mm < MPP; ++mm)
#pragma unroll
                for (int ni = 0; ni < 4; ++ni)
#pragma unroll
                    for (int ks = 0; ks < 2; ++ks)
                        acc[p * MPP + mm][ni] = MFMA16(af[mm][ks], bfrag[ni][ks], acc[p * MPP + mm][ni]);
            __builtin_amdgcn_s_setprio(0);
            __builtin_amdgcn_sched_barrier(0);
            __builtin_amdgcn_s_barrier();
        }
    }
    (void)M;

    // ---------------- epilogue ----------------
    if (MODE == 2 && col0 >= 2048) {
        // v block (BM==128 assumed for MODE 2): bounce acc through per-wave
        // LDS tile [64 dd][64 s] (16B-granular XOR swizzle), then write vt
        // (B,H,DH,S) as full 128B lines (bf16x8 per lane).
        ushort_t* vb = &lds[0][0] + w * 4096;  // 8KB per wave, K-loop LDS is dead
        const int hglob = (col0 - 2048 + wc * 64) >> 6;
        const int bidx = row0 >> 10;
        const int srow0 = (row0 & 1023) + wr * 64;
#pragma unroll
        for (int mi = 0; mi < MREP; ++mi) {
#pragma unroll
            for (int ni = 0; ni < 4; ++ni) {
                const int dd = ni * 16 + lr;
                const float bvv = bv[(hglob << 6) + dd];
                ushort4 h4;
                h4.x = f2bf(acc[mi][ni][0] + bvv);
                h4.y = f2bf(acc[mi][ni][1] + bvv);
                h4.z = f2bf(acc[mi][ni][2] + bvv);
                h4.w = f2bf(acc[mi][ni][3] + bvv);
                const int sb = mi * 32 + lh * 8;  // byte offset of s within row
                *(ushort4*)((char*)vb + dd * 128 + (sb ^ ((dd & 3) << 4))) = h4;
            }
        }
        // wave-private LDS: in-order within a wave, no barrier needed
        const int ddl = lane >> 3, s8 = lane & 7;
#pragma unroll
        for (int j = 0; j < 8; ++j) {
            const int dd = j * 8 + ddl;
            bf16x8 rowv = *(const bf16x8*)((char*)vb + dd * 128 + ((s8 * 16) ^ ((dd & 3) << 4)));
            *(bf16x8*)&vtout[(((size_t)(bidx * 16 + hglob) * 64 + dd) << 10) + srow0 + s8 * 8] = rowv;
        }
    } else {
#pragma unroll
        for (int mi = 0; mi < MREP; ++mi) {
#pragma unroll
            for (int ni = 0; ni < 4; ++ni) {
                const int col = col0 + wc * 64 + ni * 16 + lr;
                const int rowb = row0 + wr * (BM / 2) + mi * 16 + lh * 4;
                if (MODE == 2) {
                    if (col < 1024) {  // q, pre-scaled by 1/8 (exact in bf16)
                        const float bvv = bq[col];
#pragma unroll
                        for (int r = 0; r < 4; ++r)
                            qout[(size_t)(rowb + r) * 1024 + col] = f2bf((acc[mi][ni][r] + bvv) * 0.125f);
                    } else {
                        const int c = col - 1024;
                        const float bvv = bk[c];
#pragma unroll
                        for (int r = 0; r < 4; ++r)
                            kout[(size_t)(rowb + r) * 1024 + c] = f2bf(acc[mi][ni][r] + bvv);
                    }
                } else {
                    const float bvv = bias[col];
#pragma unroll
                    for (int r = 0; r < 4; ++r) {
                        float val = acc[mi][ni][r] + bvv;
                        if (RELU) val = fmaxf(val, 0.f);
                        ((ushort_t*)Cout)[(size_t)(rowb + r) * N + col] = f2bf(val);
                    }
                }
            }
        }
    }
}

// ---------------------------------------------------------------------------
// fused causal flash attention (unchanged from round 3/4 structure).
// ---------------------------------------------------------------------------
__global__ __launch_bounds__(256) void attn_kernel(const ushort_t* __restrict__ q,
                                                   const ushort_t* __restrict__ k,
                                                   const ushort_t* __restrict__ vt,
                                                   ushort_t* __restrict__ o) {
    __shared__ ushort_t ktile[64 * 64];     // 8KB, swizzled rows of 128B
    __shared__ ushort_t vtile[64 * 64];     // 8KB, V^T (dh x key), swizzled
    __shared__ ushort_t p_lds[4][16 * 64];  // 8KB, per-wave P, swizzled

    const int bh = blockIdx.x;
    const int b = bh >> 4, h = bh & 15;
    const int qt = blockIdx.y;
    const int tid = threadIdx.x, w = tid >> 6, lane = tid & 63;
    const int lr = lane & 15, lh = lane >> 4;
    const int qbase = qt * 64 + w * 16;
    const size_t headoff = (size_t)b * 1024 * 1024 + h * 64;
    const size_t vhead = (size_t)(b * 16 + h) << 16;  // *64*1024

    bf16x8 qf[2];
#pragma unroll
    for (int ks = 0; ks < 2; ++ks)
        qf[ks] = *(const bf16x8*)&q[headoff + (size_t)(qbase + lr) * 1024 + ks * 32 + lh * 8];

    f32x4 oacc[4] = {};
    float m[4] = {-INFINITY, -INFINITY, -INFINITY, -INFINITY};
    float ls[4] = {0.f, 0.f, 0.f, 0.f};

    // staging geometry: 256 threads, rows of 128B (8 lanes x 16B), 2 passes
    const int srow = tid >> 3;            // 0..31
    const int scolb = (tid & 7) * 16;     // byte col within 128B row
    const int swz0 = ((srow & 7) << 4);   // row XOR mask (same for srow, srow+32)
    char* const kbase = (char*)ktile;
    char* const vbase = (char*)vtile;
    char* const kw0 = kbase + srow * 128 + (scolb ^ swz0);
    char* const kw1 = kbase + (srow + 32) * 128 + (scolb ^ swz0);
    char* const vw0 = vbase + srow * 128 + (scolb ^ swz0);
    char* const vw1 = vbase + (srow + 32) * 128 + (scolb ^ swz0);
    const ushort_t* kg = k + headoff + (size_t)srow * 1024 + (tid & 7) * 8;
    const ushort_t* vg = vt + vhead + (size_t)srow * 1024 + (tid & 7) * 8;

    const int jmaxw = qbase + 15;       // per-wave causal bound
    const int jend = qt * 64 + 63;      // block bound

    bf16x8 sk0 = *(const bf16x8*)&kg[0];
    bf16x8 sk1 = *(const bf16x8*)&kg[32 * 1024];
    bf16x8 sv0 = *(const bf16x8*)&vg[0];
    bf16x8 sv1 = *(const bf16x8*)&vg[32 * 1024];

    for (int j0 = 0; j0 <= jend; j0 += 64) {
        __syncthreads();  // LDS safe to overwrite
        *(bf16x8*)kw0 = sk0;
        *(bf16x8*)kw1 = sk1;
        *(bf16x8*)vw0 = sv0;
        *(bf16x8*)vw1 = sv1;
        __syncthreads();
        // async-split: issue next tile's global loads now, consume next iter
        if (j0 + 64 <= jend) {
            sk0 = *(const bf16x8*)&kg[(size_t)(j0 + 64) * 1024];
            sk1 = *(const bf16x8*)&kg[(size_t)(j0 + 64) * 1024 + 32 * 1024];
            sv0 = *(const bf16x8*)&vg[j0 + 64];
            sv1 = *(const bf16x8*)&vg[32 * 1024 + j0 + 64];
        }

        if (j0 <= jmaxw) {
            // QK^T: s[kt] covers keys j0+kt*16+lr, q rows qbase+4lh+r
            f32x4 s[4] = {{0,0,0,0},{0,0,0,0},{0,0,0,0},{0,0,0,0}};
#pragma unroll
            for (int kt = 0; kt < 4; ++kt) {
                const int row = kt * 16 + lr;
                const int rswz = ((row & 7) << 4);
#pragma unroll
                for (int ks = 0; ks < 2; ++ks) {
                    bf16x8 kf = *(const bf16x8*)(kbase + row * 128 + ((ks * 64 + lh * 16) ^ rswz));
                    s[kt] = MFMA16(qf[ks], kf, s[kt]);
                }
            }
            if (j0 + 63 > qbase) {  // diagonal tile (wave-uniform): mask
#pragma unroll
                for (int kt = 0; kt < 4; ++kt)
#pragma unroll
                    for (int r = 0; r < 4; ++r)
                        s[kt][r] = ((j0 + kt * 16 + lr) <= (qbase + lh * 4 + r)) ? s[kt][r] : -1e9f;
            }
            // online softmax: row q = qbase+4lh+r lives in 16-lane groups
#pragma unroll
            for (int r = 0; r < 4; ++r) {
                float pm = fmaxf(fmaxf(s[0][r], s[1][r]), fmaxf(s[2][r], s[3][r]));
                pm = fmaxf(pm, __shfl_xor(pm, 1, 16));
                pm = fmaxf(pm, __shfl_xor(pm, 2, 16));
                pm = fmaxf(pm, __shfl_xor(pm, 4, 16));
                pm = fmaxf(pm, __shfl_xor(pm, 8, 16));
                const float mn = fmaxf(m[r], pm);
                const float corr = __expf(m[r] - mn);
                m[r] = mn;
                float p0 = __expf(s[0][r] - mn);
                float p1 = __expf(s[1][r] - mn);
                float p2 = __expf(s[2][r] - mn);
                float p3 = __expf(s[3][r] - mn);
                s[0][r] = p0; s[1][r] = p1; s[2][r] = p2; s[3][r] = p3;
                float ps = (p0 + p1) + (p2 + p3);
                ps += __shfl_xor(ps, 1, 16);
                ps += __shfl_xor(ps, 2, 16);
                ps += __shfl_xor(ps, 4, 16);
                ps += __shfl_xor(ps, 8, 16);
                ls[r] = ls[r] * corr + ps;
                oacc[0][r] *= corr; oacc[1][r] *= corr;
                oacc[2][r] *= corr; oacc[3][r] *= corr;
            }
            // P -> wave-private LDS (swizzled), then A-frag reads
            char* const pb = (char*)p_lds[w];
#pragma unroll
            for (int r = 0; r < 4; ++r) {
                const int qrow = lh * 4 + r;
                const int qswz = ((qrow & 7) << 4);
#pragma unroll
                for (int kt = 0; kt < 4; ++kt)
                    *(ushort_t*)(pb + qrow * 128 + ((kt * 32 + lr * 2) ^ qswz)) = f2bf(s[kt][r]);
            }
            const int pswz = ((lr & 7) << 4);
            bf16x8 pa0 = *(const bf16x8*)(pb + lr * 128 + ((lh * 16) ^ pswz));
            bf16x8 pa1 = *(const bf16x8*)(pb + lr * 128 + ((64 + lh * 16) ^ pswz));
#pragma unroll
            for (int dt = 0; dt < 4; ++dt) {
                const int vrow = dt * 16 + lr;
                const int vswz = ((vrow & 7) << 4);
                bf16x8 vf0 = *(const bf16x8*)(vbase + vrow * 128 + ((lh * 16) ^ vswz));
                oacc[dt] = MFMA16(pa0, vf0, oacc[dt]);
                bf16x8 vf1 = *(const bf16x8*)(vbase + vrow * 128 + ((64 + lh * 16) ^ vswz));
                oacc[dt] = MFMA16(pa1, vf1, oacc[dt]);
            }
        }
    }

    float inv[4];
#pragma unroll
    for (int r = 0; r < 4; ++r) inv[r] = 1.f / ls[r];
#pragma unroll
    for (int dt = 0; dt < 4; ++dt)
#pragma unroll
        for (int r = 0; r < 4; ++r) {
            const int row = qbase + lh * 4 + r;
            o[headoff + (size_t)row * 1024 + dt * 16 + lr] = f2bf(oacc[dt][r] * inv[r]);
        }
}

// ---------------------------------------------------------------------------
// fused residual + LayerNorm on bf16 residual stream: y = LN(t + xr).
// LAST=0: xr <- bf16(y).  LAST=1: out (f32, d_out) <- y.
// ---------------------------------------------------------------------------
template <int LAST>
__global__ __launch_bounds__(256) void add_ln(const ushort_t* __restrict__ t,
                                              ushort_t* __restrict__ xr,
                                              const float* __restrict__ g,
                                              const float* __restrict__ bb,
                                              float* __restrict__ out) {
    const int row = blockIdx.x, tid = threadIdx.x;
    const int lane = tid & 63, w = tid >> 6;
    const size_t base = (size_t)row * 1024;
    ushort4 tv = ((const ushort4*)(t + base))[tid];
    ushort4 xv = ((const ushort4*)(xr + base))[tid];
    float v0 = bf2f(tv.x) + bf2f(xv.x), v1 = bf2f(tv.y) + bf2f(xv.y);
    float v2 = bf2f(tv.z) + bf2f(xv.z), v3 = bf2f(tv.w) + bf2f(xv.w);
    float s = v0 + v1 + v2 + v3;
    float sq = v0 * v0 + v1 * v1 + v2 * v2 + v3 * v3;
#pragma unroll
    for (int off = 32; off >= 1; off >>= 1) {
        s += __shfl_xor(s, off);
        sq += __shfl_xor(sq, off);
    }
    __shared__ float red[8];
    if (lane == 0) { red[w] = s; red[4 + w] = sq; }
    __syncthreads();
    s = red[0] + red[1] + red[2] + red[3];
    sq = red[4] + red[5] + red[6] + red[7];
    const float mu = s * (1.f / 1024.f);
    const float var = sq * (1.f / 1024.f) - mu * mu;
    const float rs = rsqrtf(var + 1e-6f);
    float4 gv = ((const float4*)g)[tid];
    float4 bv = ((const float4*)bb)[tid];
    float y0 = (v0 - mu) * rs * gv.x + bv.x;
    float y1 = (v1 - mu) * rs * gv.y + bv.y;
    float y2 = (v2 - mu) * rs * gv.z + bv.z;
    float y3 = (v3 - mu) * rs * gv.w + bv.w;
    if (LAST) {
        float4 yo; yo.x = y0; yo.y = y1; yo.z = y2; yo.w = y3;
        ((float4*)(out + base))[tid] = yo;
    } else {
        ushort4 hh;
        hh.x = f2bf(y0); hh.y = f2bf(y1); hh.z = f2bf(y2); hh.w = f2bf(y3);
        ((ushort4*)(xr + base))[tid] = hh;
    }
}

// ---------------------------------------------------------------------------
extern "C" void kernel_launch(void* const* d_in, const int* in_sizes, int n_in,
                              void* d_out, int out_size, void* d_ws, size_t ws_size,
                              hipStream_t stream) {
    (void)in_sizes; (void)n_in; (void)out_size; (void)ws_size;
    const int B = 8, S = 1024, D = 1024, DFF = 4096, L = 2;
    const int M = B * S;  // 8192

    const float* x_in = (const float*)d_in[0];
    const float* Wq = (const float*)d_in[2];
    const float* bq = (const float*)d_in[3];
    const float* Wk = (const float*)d_in[4];
    const float* bk = (const float*)d_in[5];
    const float* Wv = (const float*)d_in[6];
    const float* bv = (const float*)d_in[7];
    const float* Wo = (const float*)d_in[8];
    const float* bo = (const float*)d_in[9];
    const float* W1 = (const float*)d_in[10];
    const float* b1 = (const float*)d_in[11];
    const float* W2 = (const float*)d_in[12];
    const float* b2 = (const float*)d_in[13];
    const float* ln1g = (const float*)d_in[14];
    const float* ln1b = (const float*)d_in[15];
    const float* ln2g = (const float*)d_in[16];
    const float* ln2b = (const float*)d_in[17];

    float* out = (float*)d_out;  // final f32 output only
    char* ws = (char*)d_ws;
    const size_t MB = 1024 * 1024;
    ushort_t* wqkvT = (ushort_t*)(ws + 0 * MB);   // 12MB (2 layers x 3072x1024)
    ushort_t* woT = (ushort_t*)(ws + 12 * MB);    // 4MB
    ushort_t* w1T = (ushort_t*)(ws + 16 * MB);    // 16MB
    ushort_t* w2T = (ushort_t*)(ws + 32 * MB);    // 16MB
    ushort_t* xr  = (ushort_t*)(ws + 48 * MB);    // 16MB bf16 residual stream
    ushort_t* qb  = (ushort_t*)(ws + 64 * MB);    // 16MB
    ushort_t* kb  = (ushort_t*)(ws + 80 * MB);    // 16MB
    ushort_t* vtb = (ushort_t*)(ws + 96 * MB);    // 16MB  (B,H,DH,S)
    ushort_t* ob  = (ushort_t*)(ws + 112 * MB);   // 16MB
    ushort_t* hb  = (ushort_t*)(ws + 64 * MB);    // 64MB, reuses q/k/vt/o region
    ushort_t* tb  = (ushort_t*)(ws + 128 * MB);   // 16MB bf16 pre-LN summand

    init_x<<<M * D / 4 / 256, 256, 0, stream>>>(x_in, xr, M * D / 4);
    transpose_all<<<dim3(12288, L), dim3(32, 8), 0, stream>>>(
        Wq, Wk, Wv, Wo, W1, W2, wqkvT, woT, w1T, w2T);

    for (int l = 0; l < L; ++l) {
        const size_t wOff = (size_t)l * D * D;
        const size_t bOff = (size_t)l * D;
        // QKV: M=8192, N=3072, K=1024; 128x256 tiles -> 64x12 = 768 blocks (3/CU)
        gemm8p<128, 2, 0><<<dim3(768), 512, 0, stream>>>(
            xr, wqkvT + (size_t)l * 3 * D * D, nullptr, nullptr, M, 3 * D, D, 12,
            qb, kb, vtb, bq + bOff, bk + bOff, bv + bOff);
        attn_kernel<<<dim3(B * 16, S / 64), 256, 0, stream>>>(qb, kb, vtb, ob);
        // Wo: N=1024; 128x256 tiles -> 64x4 = 256 blocks; bf16 out -> tb
        gemm8p<128, 1, 0><<<dim3(256), 512, 0, stream>>>(
            ob, woT + wOff, bo + bOff, tb, M, D, D, 4,
            nullptr, nullptr, nullptr, nullptr, nullptr, nullptr);
        add_ln<0><<<M, 256, 0, stream>>>(tb, xr, ln1g + bOff, ln1b + bOff, nullptr);
        // FFN1: N=4096; 256x256 -> 32x16 = 512 blocks (2/CU)
        gemm8p<256, 1, 1><<<dim3(512), 512, 0, stream>>>(
            xr, w1T + (size_t)l * D * DFF, b1 + (size_t)l * DFF, hb, M, DFF, D, 16,
            nullptr, nullptr, nullptr, nullptr, nullptr, nullptr);
        // FFN2: N=1024, K=4096; 128x256 -> 256 blocks; bf16 out -> tb
        gemm8p<128, 1, 0><<<dim3(256), 512, 0, stream>>>(
            hb, w2T + (size_t)l * DFF * D, b2 + bOff, tb, M, D, DFF, 4,
            nullptr, nullptr, nullptr, nullptr, nullptr, nullptr);
        if (l == L - 1)
            add_ln<1><<<M, 256, 0, stream>>>(tb, xr, ln2g + bOff, ln2b + bOff, out);
        else
            add_ln<0><<<M, 256, 0, stream>>>(tb, xr, ln2g + bOff, ln2b + bOff, nullptr);
    }
}

// Round 7
// 696.503 us; speedup vs baseline: 1.7063x; 1.0048x over previous
//
#include <hip/hip_runtime.h>

typedef __attribute__((ext_vector_type(8))) short bf16x8;
typedef __attribute__((ext_vector_type(4))) float f32x4;
typedef unsigned short ushort_t;
typedef unsigned int uint32;

#define DEV __device__ __forceinline__

// round-to-nearest-even f32 -> bf16 (bits)
DEV ushort_t f2bf(float f) {
    uint32 u = __float_as_uint(f);
    uint32 r = (u + 0x7FFFu + ((u >> 16) & 1u)) >> 16;
    return (ushort_t)r;
}
DEV float bf2f(ushort_t h) { return __uint_as_float(((uint32)h) << 16); }

#define MFMA16(a, b, c) __builtin_amdgcn_mfma_f32_16x16x32_bf16((a), (b), (c), 0, 0, 0)

DEV void gload_lds16(const void* g, void* l) {
    __builtin_amdgcn_global_load_lds((const __attribute__((address_space(1))) void*)g,
                                     (__attribute__((address_space(3))) void*)l,
                                     16, 0, 0);
}

// ---------------------------------------------------------------------------
// init: f32 x -> bf16 residual stream xr
// ---------------------------------------------------------------------------
__global__ __launch_bounds__(256) void init_x(const float* __restrict__ xin,
                                              ushort_t* __restrict__ xr, int n4) {
    int i = blockIdx.x * 256 + threadIdx.x;
    if (i >= n4) return;
    float4 v = ((const float4*)xin)[i];
    ushort4 h;
    h.x = f2bf(v.x); h.y = f2bf(v.y); h.z = f2bf(v.z); h.w = f2bf(v.w);
    ((ushort4*)xr)[i] = h;
}

// ---------------------------------------------------------------------------
// all weight transposes in ONE launch: src (K x N f32) -> dst (N x K bf16).
// grid.x = 12288 tiles (q,k,v,o: 4x1024 | W1: 4096 | W2: 4096), grid.y = layer
// ---------------------------------------------------------------------------
__global__ __launch_bounds__(256) void transpose_all(const float* __restrict__ Wq,
                                                     const float* __restrict__ Wk,
                                                     const float* __restrict__ Wv,
                                                     const float* __restrict__ Wo,
                                                     const float* __restrict__ W1,
                                                     const float* __restrict__ W2,
                                                     ushort_t* __restrict__ wqkvT,
                                                     ushort_t* __restrict__ woT,
                                                     ushort_t* __restrict__ w1T,
                                                     ushort_t* __restrict__ w2T) {
    const int l = blockIdx.y;
    const int t = blockIdx.x;
    const float* src;
    ushort_t* dst;
    int K, N, ktile, ntile;
    if (t < 4096) {
        const int which = t >> 10, tile = t & 1023;
        K = 1024; N = 1024; ktile = tile >> 5; ntile = tile & 31;
        const size_t o1 = (size_t)l * 1048576;
        if (which == 0)      { src = Wq + o1; dst = wqkvT + (size_t)l * 3145728; }
        else if (which == 1) { src = Wk + o1; dst = wqkvT + (size_t)l * 3145728 + 1048576; }
        else if (which == 2) { src = Wv + o1; dst = wqkvT + (size_t)l * 3145728 + 2097152; }
        else                 { src = Wo + o1; dst = woT + o1; }
    } else if (t < 8192) {
        const int tile = t - 4096;
        K = 1024; N = 4096; ktile = tile >> 7; ntile = tile & 127;
        src = W1 + (size_t)l * 4194304; dst = w1T + (size_t)l * 4194304;
    } else {
        const int tile = t - 8192;
        K = 4096; N = 1024; ktile = tile >> 5; ntile = tile & 31;
        src = W2 + (size_t)l * 4194304; dst = w2T + (size_t)l * 4194304;
    }
    __shared__ float tilebuf[32][33];
    const int tx = threadIdx.x, ty = threadIdx.y;  // (32,8)
    const int nt = ntile * 32, kt = ktile * 32;
#pragma unroll
    for (int j = 0; j < 4; ++j)
        tilebuf[ty + j * 8][tx] = src[(size_t)(kt + ty + j * 8) * N + nt + tx];
    __syncthreads();
#pragma unroll
    for (int j = 0; j < 4; ++j)
        dst[(size_t)(nt + ty + j * 8) * K + kt + tx] = f2bf(tilebuf[tx][ty + j * 8]);
}

// ---------------------------------------------------------------------------
// 8-phase GEMM (m201 template, plain HIP): C[M,N] = A[M,K] @ BT[N,K]^T + bias
// BM x 256 tile, BK=64, 8 waves (2M x 4N), per-wave (BM/2) x 64 C.
// PHASES/K-tile: BM=256 -> 4, BM=128 -> 2. Every phase = 16 MFMA (2 M-frags x
// 4 N-frags x 2 ks) — the m201 per-phase composition.
// Double-buffered LDS, XOR-swizzled via pre-swizzled global source.
// Counted vmcnt(4) once per K-tile; raw s_barrier; setprio around MFMA.
// MODE: 1 = bf16 out (+RELU), 2 = fused QKV split (q scaled 1/8; v -> vt via
//       per-wave LDS bounce so vt writes are full-line coalesced).
// ---------------------------------------------------------------------------
template <int BM, int MODE, int RELU>
__global__ __launch_bounds__(512, 2) void gemm8p(const ushort_t* __restrict__ A,
                                                 const ushort_t* __restrict__ BT,
                                                 const float* __restrict__ bias,
                                                 void* __restrict__ Cout,
                                                 int M, int N, int K, int gx,
                                                 ushort_t* __restrict__ qout,
                                                 ushort_t* __restrict__ kout,
                                                 ushort_t* __restrict__ vtout,
                                                 const float* __restrict__ bq,
                                                 const float* __restrict__ bk,
                                                 const float* __restrict__ bv) {
    constexpr int AH = BM / 128;        // # of 128-row A halves
    constexpr int MREP = BM / 32;       // M frags per wave
    constexpr int PHASES = (BM == 128) ? 2 : 4;
    constexpr int MPP = MREP / PHASES;  // = 2 (16 MFMA per phase)
    __shared__ ushort_t lds[2][(BM + 256) * 64];

    // XCD-aware bijective swizzle (m204)
    const int nwg = gridDim.x;
    const int q8 = nwg >> 3, r8 = nwg & 7;
    const int xcd = blockIdx.x & 7, idx = blockIdx.x >> 3;
    const int swz = (xcd < r8 ? xcd * (q8 + 1) : r8 * (q8 + 1) + (xcd - r8) * q8) + idx;
    const int bxi = swz % gx, byi = swz / gx;

    const int tid = threadIdx.x;
    const int w = tid >> 6, lane = tid & 63;
    const int wr = w >> 2, wc = w & 3;
    const int lr = lane & 15, lh = lane >> 4;
    const int row0 = byi * BM, col0 = bxi * 256;

    f32x4 acc[MREP][4] = {};

    const ushort_t* __restrict__ Ab = A + (size_t)row0 * K;
    const ushort_t* __restrict__ Bb = BT + (size_t)col0 * K;
    const int nt = K >> 6;

    const int r8l = lane >> 3;            // 0..7 row within 8-row block
    const int cu = (lane & 7) ^ r8l;      // swizzled col unit (16B)

    auto stage_half = [&](const ushort_t* src, ushort_t* lbase) {
#pragma unroll
        for (int i = 0; i < 2; ++i) {
            const int rowi = (w * 2 + i) * 8 + r8l;
            gload_lds16(src + (size_t)rowi * K + cu * 8, lbase + (w * 2 + i) * 512 + lane * 8);
        }
    };
    auto Ahalf = [&](int buf, int h) -> ushort_t* { return &lds[buf][h * 8192]; };
    auto Bhalf = [&](int buf, int h) -> ushort_t* { return &lds[buf][BM * 64 + h * 8192]; };
    auto stA = [&](int kt, int h, int buf) {
        stage_half(Ab + (size_t)h * 128 * K + (size_t)kt * 64, Ahalf(buf, h));
    };
    auto stB = [&](int kt, int h, int buf) {
        stage_half(Bb + (size_t)h * 128 * K + (size_t)kt * 64, Bhalf(buf, h));
    };

    // prologue: tile 0 (A+B) + B halves of tile 1; vmcnt(4) completes tile 0
    stB(0, 0, 0); stB(0, 1, 0);
    stA(0, 0, 0); if (AH == 2) stA(0, 1, 0);
    stB(1, 0, 1); stB(1, 1, 1);
    asm volatile("s_waitcnt vmcnt(4)" ::: "memory");
    __builtin_amdgcn_sched_barrier(0);
    __builtin_amdgcn_s_barrier();

    for (int t = 0; t < nt; ++t) {
        const int cb = t & 1, nb = cb ^ 1;
        bf16x8 bfrag[4][2];
#pragma unroll
        for (int p = 0; p < PHASES; ++p) {
            // --- ds-reads for this phase ---
            if (p == 0) {
#pragma unroll
                for (int ni = 0; ni < 4; ++ni) {
                    const int br = wc * 64 + ni * 16 + lr;
                    const ushort_t* bh = Bhalf(cb, br >> 7);
                    const int rr = br & 127;
#pragma unroll
                    for (int ks = 0; ks < 2; ++ks)
                        bfrag[ni][ks] = *(const bf16x8*)&bh[rr * 64 + (((ks * 4 + lh) ^ (rr & 7)) * 8)];
                }
            }
            bf16x8 af[MPP][2];
#pragma unroll
            for (int mm = 0; mm < MPP; ++mm) {
                const int fr = wr * (BM / 2) + (p * MPP + mm) * 16 + lr;
                const ushort_t* ah = Ahalf(cb, fr >> 7);
                const int rr = fr & 127;
#pragma unroll
                for (int ks = 0; ks < 2; ++ks)
                    af[mm][ks] = *(const bf16x8*)&ah[rr * 64 + (((ks * 4 + lh) ^ (rr & 7)) * 8)];
            }
            // --- stage half-tiles ---
            if (PHASES == 4) {
                if (p == 0) { if (t + 1 < nt) stA(t + 1, 0, nb); }
                else if (p == 1) { if (AH == 2 && t + 1 < nt) stA(t + 1, 1, nb); }
                else if (p == 2) { if (t + 2 < nt) stB(t + 2, 0, cb); }
                else {
                    if (t + 2 < nt) {
                        stB(t + 2, 1, cb);
                        asm volatile("s_waitcnt vmcnt(4)" ::: "memory");
                    } else if (t + 1 < nt) {
                        asm volatile("s_waitcnt vmcnt(0)" ::: "memory");
                    }
                }
            } else {  // PHASES == 2 (BM=128)
                if (p == 0) { if (t + 1 < nt) stA(t + 1, 0, nb); }
                else {
                    if (t + 2 < nt) {
                        stB(t + 2, 0, cb);
                        stB(t + 2, 1, cb);
                        asm volatile("s_waitcnt vmcnt(4)" ::: "memory");
                    } else if (t + 1 < nt) {
                        asm volatile("s_waitcnt vmcnt(0)" ::: "memory");
                    }
                }
            }
            __builtin_amdgcn_sched_barrier(0);
            __builtin_amdgcn_s_barrier();
            asm volatile("s_waitcnt lgkmcnt(0)" ::: "memory");
            __builtin_amdgcn_sched_barrier(0);
            __builtin_amdgcn_s_setprio(1);
#pragma unroll
            for (int mm = 0; mm < MPP; ++mm)
#pragma unroll
                for (int ni = 0; ni < 4; ++ni)
#pragma unroll
                    for (int ks = 0; ks < 2; ++ks)
                        acc[p * MPP + mm][ni] = MFMA16(af[mm][ks], bfrag[ni][ks], acc[p * MPP + mm][ni]);
            __builtin_amdgcn_s_setprio(0);
            __builtin_amdgcn_sched_barrier(0);
            __builtin_amdgcn_s_barrier();
        }
    }
    (void)M;

    // ---------------- epilogue ----------------
    if (MODE == 2 && col0 >= 2048) {
        // v block (BM==128 for MODE 2): bounce acc through per-wave LDS tile
        // [64 dd][64 s] (16B-granular XOR swizzle), then write vt (B,H,DH,S)
        // as full 128B lines (bf16x8 per lane).
        ushort_t* vb = &lds[0][0] + w * 4096;  // 8KB per wave, K-loop LDS dead
        const int hglob = (col0 - 2048 + wc * 64) >> 6;
        const int bidx = row0 >> 10;
        const int srow0 = (row0 & 1023) + wr * 64;
#pragma unroll
        for (int mi = 0; mi < MREP; ++mi) {
#pragma unroll
            for (int ni = 0; ni < 4; ++ni) {
                const int dd = ni * 16 + lr;
                const float bvv = bv[(hglob << 6) + dd];
                ushort4 h4;
                h4.x = f2bf(acc[mi][ni][0] + bvv);
                h4.y = f2bf(acc[mi][ni][1] + bvv);
                h4.z = f2bf(acc[mi][ni][2] + bvv);
                h4.w = f2bf(acc[mi][ni][3] + bvv);
                const int sb = mi * 32 + lh * 8;  // byte offset of s within row
                *(ushort4*)((char*)vb + dd * 128 + (sb ^ ((dd & 3) << 4))) = h4;
            }
        }
        // wave-private LDS: in-order within a wave, no barrier needed
        const int ddl = lane >> 3, s8 = lane & 7;
#pragma unroll
        for (int j = 0; j < 8; ++j) {
            const int dd = j * 8 + ddl;
            bf16x8 rowv = *(const bf16x8*)((char*)vb + dd * 128 + ((s8 * 16) ^ ((dd & 3) << 4)));
            *(bf16x8*)&vtout[(((size_t)(bidx * 16 + hglob) * 64 + dd) << 10) + srow0 + s8 * 8] = rowv;
        }
    } else {
#pragma unroll
        for (int mi = 0; mi < MREP; ++mi) {
#pragma unroll
            for (int ni = 0; ni < 4; ++ni) {
                const int col = col0 + wc * 64 + ni * 16 + lr;
                const int rowb = row0 + wr * (BM / 2) + mi * 16 + lh * 4;
                if (MODE == 2) {
                    if (col < 1024) {  // q, pre-scaled by 1/8 (exact in bf16)
                        const float bvv = bq[col];
#pragma unroll
                        for (int r = 0; r < 4; ++r)
                            qout[(size_t)(rowb + r) * 1024 + col] = f2bf((acc[mi][ni][r] + bvv) * 0.125f);
                    } else {
                        const int c = col - 1024;
                        const float bvv = bk[c];
#pragma unroll
                        for (int r = 0; r < 4; ++r)
                            kout[(size_t)(rowb + r) * 1024 + c] = f2bf(acc[mi][ni][r] + bvv);
                    }
                } else {
                    const float bvv = bias[col];
#pragma unroll
                    for (int r = 0; r < 4; ++r) {
                        float val = acc[mi][ni][r] + bvv;
                        if (RELU) val = fmaxf(val, 0.f);
                        ((ushort_t*)Cout)[(size_t)(rowb + r) * N + col] = f2bf(val);
                    }
                }
            }
        }
    }
}

// ---------------------------------------------------------------------------
// fused causal flash attention (unchanged).
// ---------------------------------------------------------------------------
__global__ __launch_bounds__(256) void attn_kernel(const ushort_t* __restrict__ q,
                                                   const ushort_t* __restrict__ k,
                                                   const ushort_t* __restrict__ vt,
                                                   ushort_t* __restrict__ o) {
    __shared__ ushort_t ktile[64 * 64];     // 8KB, swizzled rows of 128B
    __shared__ ushort_t vtile[64 * 64];     // 8KB, V^T (dh x key), swizzled
    __shared__ ushort_t p_lds[4][16 * 64];  // 8KB, per-wave P, swizzled

    const int bh = blockIdx.x;
    const int b = bh >> 4, h = bh & 15;
    const int qt = blockIdx.y;
    const int tid = threadIdx.x, w = tid >> 6, lane = tid & 63;
    const int lr = lane & 15, lh = lane >> 4;
    const int qbase = qt * 64 + w * 16;
    const size_t headoff = (size_t)b * 1024 * 1024 + h * 64;
    const size_t vhead = (size_t)(b * 16 + h) << 16;  // *64*1024

    bf16x8 qf[2];
#pragma unroll
    for (int ks = 0; ks < 2; ++ks)
        qf[ks] = *(const bf16x8*)&q[headoff + (size_t)(qbase + lr) * 1024 + ks * 32 + lh * 8];

    f32x4 oacc[4] = {};
    float m[4] = {-INFINITY, -INFINITY, -INFINITY, -INFINITY};
    float ls[4] = {0.f, 0.f, 0.f, 0.f};

    // staging geometry: 256 threads, rows of 128B (8 lanes x 16B), 2 passes
    const int srow = tid >> 3;            // 0..31
    const int scolb = (tid & 7) * 16;     // byte col within 128B row
    const int swz0 = ((srow & 7) << 4);   // row XOR mask (same for srow, srow+32)
    char* const kbase = (char*)ktile;
    char* const vbase = (char*)vtile;
    char* const kw0 = kbase + srow * 128 + (scolb ^ swz0);
    char* const kw1 = kbase + (srow + 32) * 128 + (scolb ^ swz0);
    char* const vw0 = vbase + srow * 128 + (scolb ^ swz0);
    char* const vw1 = vbase + (srow + 32) * 128 + (scolb ^ swz0);
    const ushort_t* kg = k + headoff + (size_t)srow * 1024 + (tid & 7) * 8;
    const ushort_t* vg = vt + vhead + (size_t)srow * 1024 + (tid & 7) * 8;

    const int jmaxw = qbase + 15;       // per-wave causal bound
    const int jend = qt * 64 + 63;      // block bound

    bf16x8 sk0 = *(const bf16x8*)&kg[0];
    bf16x8 sk1 = *(const bf16x8*)&kg[32 * 1024];
    bf16x8 sv0 = *(const bf16x8*)&vg[0];
    bf16x8 sv1 = *(const bf16x8*)&vg[32 * 1024];

    for (int j0 = 0; j0 <= jend; j0 += 64) {
        __syncthreads();  // LDS safe to overwrite
        *(bf16x8*)kw0 = sk0;
        *(bf16x8*)kw1 = sk1;
        *(bf16x8*)vw0 = sv0;
        *(bf16x8*)vw1 = sv1;
        __syncthreads();
        // async-split: issue next tile's global loads now, consume next iter
        if (j0 + 64 <= jend) {
            sk0 = *(const bf16x8*)&kg[(size_t)(j0 + 64) * 1024];
            sk1 = *(const bf16x8*)&kg[(size_t)(j0 + 64) * 1024 + 32 * 1024];
            sv0 = *(const bf16x8*)&vg[j0 + 64];
            sv1 = *(const bf16x8*)&vg[32 * 1024 + j0 + 64];
        }

        if (j0 <= jmaxw) {
            // QK^T: s[kt] covers keys j0+kt*16+lr, q rows qbase+4lh+r
            f32x4 s[4] = {{0,0,0,0},{0,0,0,0},{0,0,0,0},{0,0,0,0}};
#pragma unroll
            for (int kt = 0; kt < 4; ++kt) {
                const int row = kt * 16 + lr;
                const int rswz = ((row & 7) << 4);
#pragma unroll
                for (int ks = 0; ks < 2; ++ks) {
                    bf16x8 kf = *(const bf16x8*)(kbase + row * 128 + ((ks * 64 + lh * 16) ^ rswz));
                    s[kt] = MFMA16(qf[ks], kf, s[kt]);
                }
            }
            if (j0 + 63 > qbase) {  // diagonal tile (wave-uniform): mask
#pragma unroll
                for (int kt = 0; kt < 4; ++kt)
#pragma unroll
                    for (int r = 0; r < 4; ++r)
                        s[kt][r] = ((j0 + kt * 16 + lr) <= (qbase + lh * 4 + r)) ? s[kt][r] : -1e9f;
            }
            // online softmax: row q = qbase+4lh+r lives in 16-lane groups
#pragma unroll
            for (int r = 0; r < 4; ++r) {
                float pm = fmaxf(fmaxf(s[0][r], s[1][r]), fmaxf(s[2][r], s[3][r]));
                pm = fmaxf(pm, __shfl_xor(pm, 1, 16));
                pm = fmaxf(pm, __shfl_xor(pm, 2, 16));
                pm = fmaxf(pm, __shfl_xor(pm, 4, 16));
                pm = fmaxf(pm, __shfl_xor(pm, 8, 16));
                const float mn = fmaxf(m[r], pm);
                const float corr = __expf(m[r] - mn);
                m[r] = mn;
                float p0 = __expf(s[0][r] - mn);
                float p1 = __expf(s[1][r] - mn);
                float p2 = __expf(s[2][r] - mn);
                float p3 = __expf(s[3][r] - mn);
                s[0][r] = p0; s[1][r] = p1; s[2][r] = p2; s[3][r] = p3;
                float ps = (p0 + p1) + (p2 + p3);
                ps += __shfl_xor(ps, 1, 16);
                ps += __shfl_xor(ps, 2, 16);
                ps += __shfl_xor(ps, 4, 16);
                ps += __shfl_xor(ps, 8, 16);
                ls[r] = ls[r] * corr + ps;
                oacc[0][r] *= corr; oacc[1][r] *= corr;
                oacc[2][r] *= corr; oacc[3][r] *= corr;
            }
            // P -> wave-private LDS (swizzled), then A-frag reads
            char* const pb = (char*)p_lds[w];
#pragma unroll
            for (int r = 0; r < 4; ++r) {
                const int qrow = lh * 4 + r;
                const int qswz = ((qrow & 7) << 4);
#pragma unroll
                for (int kt = 0; kt < 4; ++kt)
                    *(ushort_t*)(pb + qrow * 128 + ((kt * 32 + lr * 2) ^ qswz)) = f2bf(s[kt][r]);
            }
            const int pswz = ((lr & 7) << 4);
            bf16x8 pa0 = *(const bf16x8*)(pb + lr * 128 + ((lh * 16) ^ pswz));
            bf16x8 pa1 = *(const bf16x8*)(pb + lr * 128 + ((64 + lh * 16) ^ pswz));
#pragma unroll
            for (int dt = 0; dt < 4; ++dt) {
                const int vrow = dt * 16 + lr;
                const int vswz = ((vrow & 7) << 4);
                bf16x8 vf0 = *(const bf16x8*)(vbase + vrow * 128 + ((lh * 16) ^ vswz));
                oacc[dt] = MFMA16(pa0, vf0, oacc[dt]);
                bf16x8 vf1 = *(const bf16x8*)(vbase + vrow * 128 + ((64 + lh * 16) ^ vswz));
                oacc[dt] = MFMA16(pa1, vf1, oacc[dt]);
            }
        }
    }

    float inv[4];
#pragma unroll
    for (int r = 0; r < 4; ++r) inv[r] = 1.f / ls[r];
#pragma unroll
    for (int dt = 0; dt < 4; ++dt)
#pragma unroll
        for (int r = 0; r < 4; ++r) {
            const int row = qbase + lh * 4 + r;
            o[headoff + (size_t)row * 1024 + dt * 16 + lr] = f2bf(oacc[dt][r] * inv[r]);
        }
}

// ---------------------------------------------------------------------------
// fused residual + LayerNorm on bf16 residual stream: y = LN(t + xr).
// LAST=0: xr <- bf16(y).  LAST=1: out (f32, d_out) <- y.
// ---------------------------------------------------------------------------
template <int LAST>
__global__ __launch_bounds__(256) void add_ln(const ushort_t* __restrict__ t,
                                              ushort_t* __restrict__ xr,
                                              const float* __restrict__ g,
                                              const float* __restrict__ bb,
                                              float* __restrict__ out) {
    const int row = blockIdx.x, tid = threadIdx.x;
    const int lane = tid & 63, w = tid >> 6;
    const size_t base = (size_t)row * 1024;
    ushort4 tv = ((const ushort4*)(t + base))[tid];
    ushort4 xv = ((const ushort4*)(xr + base))[tid];
    float v0 = bf2f(tv.x) + bf2f(xv.x), v1 = bf2f(tv.y) + bf2f(xv.y);
    float v2 = bf2f(tv.z) + bf2f(xv.z), v3 = bf2f(tv.w) + bf2f(xv.w);
    float s = v0 + v1 + v2 + v3;
    float sq = v0 * v0 + v1 * v1 + v2 * v2 + v3 * v3;
#pragma unroll
    for (int off = 32; off >= 1; off >>= 1) {
        s += __shfl_xor(s, off);
        sq += __shfl_xor(sq, off);
    }
    __shared__ float red[8];
    if (lane == 0) { red[w] = s; red[4 + w] = sq; }
    __syncthreads();
    s = red[0] + red[1] + red[2] + red[3];
    sq = red[4] + red[5] + red[6] + red[7];
    const float mu = s * (1.f / 1024.f);
    const float var = sq * (1.f / 1024.f) - mu * mu;
    const float rs = rsqrtf(var + 1e-6f);
    float4 gv = ((const float4*)g)[tid];
    float4 bv = ((const float4*)bb)[tid];
    float y0 = (v0 - mu) * rs * gv.x + bv.x;
    float y1 = (v1 - mu) * rs * gv.y + bv.y;
    float y2 = (v2 - mu) * rs * gv.z + bv.z;
    float y3 = (v3 - mu) * rs * gv.w + bv.w;
    if (LAST) {
        float4 yo; yo.x = y0; yo.y = y1; yo.z = y2; yo.w = y3;
        ((float4*)(out + base))[tid] = yo;
    } else {
        ushort4 hh;
        hh.x = f2bf(y0); hh.y = f2bf(y1); hh.z = f2bf(y2); hh.w = f2bf(y3);
        ((ushort4*)(xr + base))[tid] = hh;
    }
}

// ---------------------------------------------------------------------------
extern "C" void kernel_launch(void* const* d_in, const int* in_sizes, int n_in,
                              void* d_out, int out_size, void* d_ws, size_t ws_size,
                              hipStream_t stream) {
    (void)in_sizes; (void)n_in; (void)out_size; (void)ws_size;
    const int B = 8, S = 1024, D = 1024, DFF = 4096, L = 2;
    const int M = B * S;  // 8192

    const float* x_in = (const float*)d_in[0];
    const float* Wq = (const float*)d_in[2];
    const float* bq = (const float*)d_in[3];
    const float* Wk = (const float*)d_in[4];
    const float* bk = (const float*)d_in[5];
    const float* Wv = (const float*)d_in[6];
    const float* bv = (const float*)d_in[7];
    const float* Wo = (const float*)d_in[8];
    const float* bo = (const float*)d_in[9];
    const float* W1 = (const float*)d_in[10];
    const float* b1 = (const float*)d_in[11];
    const float* W2 = (const float*)d_in[12];
    const float* b2 = (const float*)d_in[13];
    const float* ln1g = (const float*)d_in[14];
    const float* ln1b = (const float*)d_in[15];
    const float* ln2g = (const float*)d_in[16];
    const float* ln2b = (const float*)d_in[17];

    float* out = (float*)d_out;  // final f32 output only
    char* ws = (char*)d_ws;
    const size_t MB = 1024 * 1024;
    ushort_t* wqkvT = (ushort_t*)(ws + 0 * MB);   // 12MB (2 layers x 3072x1024)
    ushort_t* woT = (ushort_t*)(ws + 12 * MB);    // 4MB
    ushort_t* w1T = (ushort_t*)(ws + 16 * MB);    // 16MB
    ushort_t* w2T = (ushort_t*)(ws + 32 * MB);    // 16MB
    ushort_t* xr  = (ushort_t*)(ws + 48 * MB);    // 16MB bf16 residual stream
    ushort_t* qb  = (ushort_t*)(ws + 64 * MB);    // 16MB
    ushort_t* kb  = (ushort_t*)(ws + 80 * MB);    // 16MB
    ushort_t* vtb = (ushort_t*)(ws + 96 * MB);    // 16MB  (B,H,DH,S)
    ushort_t* ob  = (ushort_t*)(ws + 112 * MB);   // 16MB
    ushort_t* hb  = (ushort_t*)(ws + 64 * MB);    // 64MB, reuses q/k/vt/o region
    ushort_t* tb  = (ushort_t*)(ws + 128 * MB);   // 16MB bf16 pre-LN summand

    init_x<<<M * D / 4 / 256, 256, 0, stream>>>(x_in, xr, M * D / 4);
    transpose_all<<<dim3(12288, L), dim3(32, 8), 0, stream>>>(
        Wq, Wk, Wv, Wo, W1, W2, wqkvT, woT, w1T, w2T);

    for (int l = 0; l < L; ++l) {
        const size_t wOff = (size_t)l * D * D;
        const size_t bOff = (size_t)l * D;
        // QKV: M=8192, N=3072, K=1024; 128x256 tiles -> 64x12 = 768 blocks (3/CU)
        gemm8p<128, 2, 0><<<dim3(768), 512, 0, stream>>>(
            xr, wqkvT + (size_t)l * 3 * D * D, nullptr, nullptr, M, 3 * D, D, 12,
            qb, kb, vtb, bq + bOff, bk + bOff, bv + bOff);
        attn_kernel<<<dim3(B * 16, S / 64), 256, 0, stream>>>(qb, kb, vtb, ob);
        // Wo: N=1024; 128x256 tiles -> 64x4 = 256 blocks; bf16 out -> tb
        gemm8p<128, 1, 0><<<dim3(256), 512, 0, stream>>>(
            ob, woT + wOff, bo + bOff, tb, M, D, D, 4,
            nullptr, nullptr, nullptr, nullptr, nullptr, nullptr);
        add_ln<0><<<M, 256, 0, stream>>>(tb, xr, ln1g + bOff, ln1b + bOff, nullptr);
        // FFN1: N=4096; 256x256 -> 32x16 = 512 blocks (2 rounds)
        gemm8p<256, 1, 1><<<dim3(512), 512, 0, stream>>>(
            xr, w1T + (size_t)l * D * DFF, b1 + (size_t)l * DFF, hb, M, DFF, D, 16,
            nullptr, nullptr, nullptr, nullptr, nullptr, nullptr);
        // FFN2: N=1024, K=4096; 128x256 -> 256 blocks; bf16 out -> tb
        gemm8p<128, 1, 0><<<dim3(256), 512, 0, stream>>>(
            hb, w2T + (size_t)l * DFF * D, b2 + bOff, tb, M, D, DFF, 4,
            nullptr, nullptr, nullptr, nullptr, nullptr, nullptr);
        if (l == L - 1)
            add_ln<1><<<M, 256, 0, stream>>>(tb, xr, ln2g + bOff, ln2b + bOff, out);
        else
            add_ln<0><<<M, 256, 0, stream>>>(tb, xr, ln2g + bOff, ln2b + bOff, nullptr);
    }
}

// Round 8
// 679.891 us; speedup vs baseline: 1.7480x; 1.0244x over previous
//
#include <hip/hip_runtime.h>

typedef __attribute__((ext_vector_type(8))) short bf16x8;
typedef __attribute__((ext_vector_type(4))) float f32x4;
typedef unsigned short ushort_t;
typedef unsigned int uint32;

#define DEV __device__ __forceinline__

// round-to-nearest-even f32 -> bf16 (bits)
DEV ushort_t f2bf(float f) {
    uint32 u = __float_as_uint(f);
    uint32 r = (u + 0x7FFFu + ((u >> 16) & 1u)) >> 16;
    return (ushort_t)r;
}
DEV float bf2f(ushort_t h) { return __uint_as_float(((uint32)h) << 16); }

#define MFMA16(a, b, c) __builtin_amdgcn_mfma_f32_16x16x32_bf16((a), (b), (c), 0, 0, 0)

DEV void gload_lds16(const void* g, void* l) {
    __builtin_amdgcn_global_load_lds((const __attribute__((address_space(1))) void*)g,
                                     (__attribute__((address_space(3))) void*)l,
                                     16, 0, 0);
}

// ---------------------------------------------------------------------------
// init: f32 x -> bf16 residual stream xr
// ---------------------------------------------------------------------------
__global__ __launch_bounds__(256) void init_x(const float* __restrict__ xin,
                                              ushort_t* __restrict__ xr, int n4) {
    int i = blockIdx.x * 256 + threadIdx.x;
    if (i >= n4) return;
    float4 v = ((const float4*)xin)[i];
    ushort4 h;
    h.x = f2bf(v.x); h.y = f2bf(v.y); h.z = f2bf(v.z); h.w = f2bf(v.w);
    ((ushort4*)xr)[i] = h;
}

// ---------------------------------------------------------------------------
// all weight transposes in ONE launch: src (K x N f32) -> dst (N x K bf16).
// grid.x = 12288 tiles (q,k,v,o: 4x1024 | W1: 4096 | W2: 4096), grid.y = layer
// ---------------------------------------------------------------------------
__global__ __launch_bounds__(256) void transpose_all(const float* __restrict__ Wq,
                                                     const float* __restrict__ Wk,
                                                     const float* __restrict__ Wv,
                                                     const float* __restrict__ Wo,
                                                     const float* __restrict__ W1,
                                                     const float* __restrict__ W2,
                                                     ushort_t* __restrict__ wqkvT,
                                                     ushort_t* __restrict__ woT,
                                                     ushort_t* __restrict__ w1T,
                                                     ushort_t* __restrict__ w2T) {
    const int l = blockIdx.y;
    const int t = blockIdx.x;
    const float* src;
    ushort_t* dst;
    int K, N, ktile, ntile;
    if (t < 4096) {
        const int which = t >> 10, tile = t & 1023;
        K = 1024; N = 1024; ktile = tile >> 5; ntile = tile & 31;
        const size_t o1 = (size_t)l * 1048576;
        if (which == 0)      { src = Wq + o1; dst = wqkvT + (size_t)l * 3145728; }
        else if (which == 1) { src = Wk + o1; dst = wqkvT + (size_t)l * 3145728 + 1048576; }
        else if (which == 2) { src = Wv + o1; dst = wqkvT + (size_t)l * 3145728 + 2097152; }
        else                 { src = Wo + o1; dst = woT + o1; }
    } else if (t < 8192) {
        const int tile = t - 4096;
        K = 1024; N = 4096; ktile = tile >> 7; ntile = tile & 127;
        src = W1 + (size_t)l * 4194304; dst = w1T + (size_t)l * 4194304;
    } else {
        const int tile = t - 8192;
        K = 4096; N = 1024; ktile = tile >> 5; ntile = tile & 31;
        src = W2 + (size_t)l * 4194304; dst = w2T + (size_t)l * 4194304;
    }
    __shared__ float tilebuf[32][33];
    const int tx = threadIdx.x, ty = threadIdx.y;  // (32,8)
    const int nt = ntile * 32, kt = ktile * 32;
#pragma unroll
    for (int j = 0; j < 4; ++j)
        tilebuf[ty + j * 8][tx] = src[(size_t)(kt + ty + j * 8) * N + nt + tx];
    __syncthreads();
#pragma unroll
    for (int j = 0; j < 4; ++j)
        dst[(size_t)(nt + ty + j * 8) * K + kt + tx] = f2bf(tilebuf[tx][ty + j * 8]);
}

// ---------------------------------------------------------------------------
// 8-phase GEMM (m201 template, plain HIP): C[M,N] = A[M,K] @ BT[N,K]^T + bias
// BM x 256 tile, BK=64, 8 waves (2M x 4N), per-wave (BM/2) x 64 C.
// PHASES/K-tile: BM=256 -> 4, BM=128 -> 2; every phase = 16 MFMA.
// K-loop unrolled by 2 so double-buffer indices are compile-time; staging via
// incremental per-lane pointers; ds_read offsets precomputed (VALU-light).
// Double-buffered LDS, XOR-swizzled via pre-swizzled global source.
// Counted vmcnt(4) once per K-tile; raw s_barrier; setprio around MFMA.
// MODE: 1 = bf16 out (+RELU), 2 = fused QKV split (q scaled 1/8; v -> vt via
//       per-wave LDS bounce so vt writes are full-line coalesced).
// ---------------------------------------------------------------------------
template <int BM, int MODE, int RELU>
__global__ __launch_bounds__(512, 2) void gemm8p(const ushort_t* __restrict__ A,
                                                 const ushort_t* __restrict__ BT,
                                                 const float* __restrict__ bias,
                                                 void* __restrict__ Cout,
                                                 int M, int N, int K, int gx,
                                                 ushort_t* __restrict__ qout,
                                                 ushort_t* __restrict__ kout,
                                                 ushort_t* __restrict__ vtout,
                                                 const float* __restrict__ bq,
                                                 const float* __restrict__ bk,
                                                 const float* __restrict__ bv) {
    constexpr int AH = BM / 128;        // # of 128-row A halves
    constexpr int MREP = BM / 32;       // M frags per wave
    constexpr int PHASES = (BM == 128) ? 2 : 4;
    constexpr int MPP = MREP / PHASES;  // = 2 (16 MFMA per phase)
    __shared__ ushort_t lds[2][(BM + 256) * 64];

    // XCD-aware bijective swizzle (m204)
    const int nwg = gridDim.x;
    const int q8 = nwg >> 3, r8 = nwg & 7;
    const int xcd = blockIdx.x & 7, idx = blockIdx.x >> 3;
    const int swz = (xcd < r8 ? xcd * (q8 + 1) : r8 * (q8 + 1) + (xcd - r8) * q8) + idx;
    const int bxi = swz % gx, byi = swz / gx;

    const int tid = threadIdx.x;
    const int w = tid >> 6, lane = tid & 63;
    const int wr = w >> 2, wc = w & 3;
    const int lr = lane & 15, lh = lane >> 4;
    const int row0 = byi * BM, col0 = bxi * 256;

    f32x4 acc[MREP][4] = {};

    const ushort_t* __restrict__ Ab = A + (size_t)row0 * K;
    const ushort_t* __restrict__ Bb = BT + (size_t)col0 * K;
    const int nt = K >> 6;

    const int r8l = lane >> 3;            // 0..7 row within 8-row block
    const int cu = (lane & 7) ^ r8l;      // swizzled col unit (16B)
    const int so = w * 1024 + lane * 8;   // LDS dest elem offset within half

    // incremental per-lane global stage pointers (advance +64 per staged tile)
    const ushort_t* aS[AH][2];
    const ushort_t* bS[2][2];
#pragma unroll
    for (int h2 = 0; h2 < AH; ++h2)
#pragma unroll
        for (int i = 0; i < 2; ++i)
            aS[h2][i] = Ab + (size_t)(h2 * 128 + (w * 2 + i) * 8 + r8l) * K + cu * 8;
#pragma unroll
    for (int h2 = 0; h2 < 2; ++h2)
#pragma unroll
        for (int i = 0; i < 2; ++i)
            bS[h2][i] = Bb + (size_t)(h2 * 128 + (w * 2 + i) * 8 + r8l) * K + cu * 8;

    auto stageA = [&](int buf, int h2) {
#pragma unroll
        for (int i = 0; i < 2; ++i) {
            gload_lds16(aS[h2][i], &lds[buf][h2 * 8192 + so + i * 512]);
            aS[h2][i] += 64;
        }
    };
    auto stageB = [&](int buf, int h2) {
#pragma unroll
        for (int i = 0; i < 2; ++i) {
            gload_lds16(bS[h2][i], &lds[buf][BM * 64 + h2 * 8192 + so + i * 512]);
            bS[h2][i] += 64;
        }
    };

    // precomputed swizzled ds_read offsets (elements)
    int boff[4][2];
#pragma unroll
    for (int ni = 0; ni < 4; ++ni) {
        const int br = wc * 64 + ni * 16 + lr;
        const int rr = br & 127, bh2 = br >> 7;
#pragma unroll
        for (int ks = 0; ks < 2; ++ks)
            boff[ni][ks] = BM * 64 + bh2 * 8192 + rr * 64 + (((ks * 4 + lh) ^ (rr & 7)) * 8);
    }
    int aoff[MREP][2];
#pragma unroll
    for (int mi = 0; mi < MREP; ++mi) {
        const int fr = wr * (BM / 2) + mi * 16 + lr;
        const int rr = fr & 127, fh = fr >> 7;
#pragma unroll
        for (int ks = 0; ks < 2; ++ks)
            aoff[mi][ks] = fh * 8192 + rr * 64 + (((ks * 4 + lh) ^ (rr & 7)) * 8);
    }

    // prologue: tile 0 (B+A) + B halves of tile 1; vmcnt(4) completes tile 0
    stageB(0, 0); stageB(0, 1);
    stageA(0, 0); if (AH == 2) stageA(0, 1);
    stageB(1, 0); stageB(1, 1);
    asm volatile("s_waitcnt vmcnt(4)" ::: "memory");
    __builtin_amdgcn_sched_barrier(0);
    __builtin_amdgcn_s_barrier();

    for (int t2 = 0; t2 < nt; t2 += 2) {
#pragma unroll
        for (int ti = 0; ti < 2; ++ti) {   // ti constant after unroll: cb=ti, nb=1-ti
            const int t = t2 + ti;
            bf16x8 bfrag[4][2];
#pragma unroll
            for (int p = 0; p < PHASES; ++p) {
                if (p == 0) {
#pragma unroll
                    for (int ni = 0; ni < 4; ++ni)
#pragma unroll
                        for (int ks = 0; ks < 2; ++ks)
                            bfrag[ni][ks] = *(const bf16x8*)&lds[ti][boff[ni][ks]];
                }
                bf16x8 af[MPP][2];
#pragma unroll
                for (int mm = 0; mm < MPP; ++mm)
#pragma unroll
                    for (int ks = 0; ks < 2; ++ks)
                        af[mm][ks] = *(const bf16x8*)&lds[ti][aoff[p * MPP + mm][ks]];
                // --- stage half-tiles (same schedule as verified r4-r6) ---
                if (PHASES == 4) {
                    if (p == 0) { if (t + 1 < nt) stageA(1 - ti, 0); }
                    else if (p == 1) { if (AH == 2 && t + 1 < nt) stageA(1 - ti, 1); }
                    else if (p == 2) { if (t + 2 < nt) stageB(ti, 0); }
                    else {
                        if (t + 2 < nt) {
                            stageB(ti, 1);
                            asm volatile("s_waitcnt vmcnt(4)" ::: "memory");
                        } else if (t + 1 < nt) {
                            asm volatile("s_waitcnt vmcnt(0)" ::: "memory");
                        }
                    }
                } else {  // PHASES == 2 (BM=128)
                    if (p == 0) { if (t + 1 < nt) stageA(1 - ti, 0); }
                    else {
                        if (t + 2 < nt) {
                            stageB(ti, 0);
                            stageB(ti, 1);
                            asm volatile("s_waitcnt vmcnt(4)" ::: "memory");
                        } else if (t + 1 < nt) {
                            asm volatile("s_waitcnt vmcnt(0)" ::: "memory");
                        }
                    }
                }
                __builtin_amdgcn_sched_barrier(0);
                __builtin_amdgcn_s_barrier();
                asm volatile("s_waitcnt lgkmcnt(0)" ::: "memory");
                __builtin_amdgcn_sched_barrier(0);
                __builtin_amdgcn_s_setprio(1);
#pragma unroll
                for (int mm = 0; mm < MPP; ++mm)
#pragma unroll
                    for (int ni = 0; ni < 4; ++ni)
#pragma unroll
                        for (int ks = 0; ks < 2; ++ks)
                            acc[p * MPP + mm][ni] = MFMA16(af[mm][ks], bfrag[ni][ks], acc[p * MPP + mm][ni]);
                __builtin_amdgcn_s_setprio(0);
                __builtin_amdgcn_sched_barrier(0);
                __builtin_amdgcn_s_barrier();
            }
        }
    }
    (void)M;

    // ---------------- epilogue ----------------
    if (MODE == 2 && col0 >= 2048) {
        // v block (BM==128 for MODE 2): bounce acc through per-wave LDS tile
        // [64 dd][64 s] (16B-granular XOR swizzle), then write vt (B,H,DH,S)
        // as full 128B lines (bf16x8 per lane).
        ushort_t* vb = &lds[0][0] + w * 4096;  // 8KB per wave, K-loop LDS dead
        const int hglob = (col0 - 2048 + wc * 64) >> 6;
        const int bidx = row0 >> 10;
        const int srow0 = (row0 & 1023) + wr * 64;
#pragma unroll
        for (int mi = 0; mi < MREP; ++mi) {
#pragma unroll
            for (int ni = 0; ni < 4; ++ni) {
                const int dd = ni * 16 + lr;
                const float bvv = bv[(hglob << 6) + dd];
                ushort4 h4;
                h4.x = f2bf(acc[mi][ni][0] + bvv);
                h4.y = f2bf(acc[mi][ni][1] + bvv);
                h4.z = f2bf(acc[mi][ni][2] + bvv);
                h4.w = f2bf(acc[mi][ni][3] + bvv);
                const int sb = mi * 32 + lh * 8;  // byte offset of s within row
                *(ushort4*)((char*)vb + dd * 128 + (sb ^ ((dd & 3) << 4))) = h4;
            }
        }
        // wave-private LDS: in-order within a wave, no barrier needed
        const int ddl = lane >> 3, s8 = lane & 7;
#pragma unroll
        for (int j = 0; j < 8; ++j) {
            const int dd = j * 8 + ddl;
            bf16x8 rowv = *(const bf16x8*)((char*)vb + dd * 128 + ((s8 * 16) ^ ((dd & 3) << 4)));
            *(bf16x8*)&vtout[(((size_t)(bidx * 16 + hglob) * 64 + dd) << 10) + srow0 + s8 * 8] = rowv;
        }
    } else {
#pragma unroll
        for (int mi = 0; mi < MREP; ++mi) {
#pragma unroll
            for (int ni = 0; ni < 4; ++ni) {
                const int col = col0 + wc * 64 + ni * 16 + lr;
                const int rowb = row0 + wr * (BM / 2) + mi * 16 + lh * 4;
                if (MODE == 2) {
                    if (col < 1024) {  // q, pre-scaled by 1/8 (exact in bf16)
                        const float bvv = bq[col];
#pragma unroll
                        for (int r = 0; r < 4; ++r)
                            qout[(size_t)(rowb + r) * 1024 + col] = f2bf((acc[mi][ni][r] + bvv) * 0.125f);
                    } else {
                        const int c = col - 1024;
                        const float bvv = bk[c];
#pragma unroll
                        for (int r = 0; r < 4; ++r)
                            kout[(size_t)(rowb + r) * 1024 + c] = f2bf(acc[mi][ni][r] + bvv);
                    }
                } else {
                    const float bvv = bias[col];
#pragma unroll
                    for (int r = 0; r < 4; ++r) {
                        float val = acc[mi][ni][r] + bvv;
                        if (RELU) val = fmaxf(val, 0.f);
                        ((ushort_t*)Cout)[(size_t)(rowb + r) * N + col] = f2bf(val);
                    }
                }
            }
        }
    }
}

// ---------------------------------------------------------------------------
// fused causal flash attention (unchanged).
// ---------------------------------------------------------------------------
__global__ __launch_bounds__(256) void attn_kernel(const ushort_t* __restrict__ q,
                                                   const ushort_t* __restrict__ k,
                                                   const ushort_t* __restrict__ vt,
                                                   ushort_t* __restrict__ o) {
    __shared__ ushort_t ktile[64 * 64];     // 8KB, swizzled rows of 128B
    __shared__ ushort_t vtile[64 * 64];     // 8KB, V^T (dh x key), swizzled
    __shared__ ushort_t p_lds[4][16 * 64];  // 8KB, per-wave P, swizzled

    const int bh = blockIdx.x;
    const int b = bh >> 4, h = bh & 15;
    const int qt = blockIdx.y;
    const int tid = threadIdx.x, w = tid >> 6, lane = tid & 63;
    const int lr = lane & 15, lh = lane >> 4;
    const int qbase = qt * 64 + w * 16;
    const size_t headoff = (size_t)b * 1024 * 1024 + h * 64;
    const size_t vhead = (size_t)(b * 16 + h) << 16;  // *64*1024

    bf16x8 qf[2];
#pragma unroll
    for (int ks = 0; ks < 2; ++ks)
        qf[ks] = *(const bf16x8*)&q[headoff + (size_t)(qbase + lr) * 1024 + ks * 32 + lh * 8];

    f32x4 oacc[4] = {};
    float m[4] = {-INFINITY, -INFINITY, -INFINITY, -INFINITY};
    float ls[4] = {0.f, 0.f, 0.f, 0.f};

    // staging geometry: 256 threads, rows of 128B (8 lanes x 16B), 2 passes
    const int srow = tid >> 3;            // 0..31
    const int scolb = (tid & 7) * 16;     // byte col within 128B row
    const int swz0 = ((srow & 7) << 4);   // row XOR mask (same for srow, srow+32)
    char* const kbase = (char*)ktile;
    char* const vbase = (char*)vtile;
    char* const kw0 = kbase + srow * 128 + (scolb ^ swz0);
    char* const kw1 = kbase + (srow + 32) * 128 + (scolb ^ swz0);
    char* const vw0 = vbase + srow * 128 + (scolb ^ swz0);
    char* const vw1 = vbase + (srow + 32) * 128 + (scolb ^ swz0);
    const ushort_t* kg = k + headoff + (size_t)srow * 1024 + (tid & 7) * 8;
    const ushort_t* vg = vt + vhead + (size_t)srow * 1024 + (tid & 7) * 8;

    const int jmaxw = qbase + 15;       // per-wave causal bound
    const int jend = qt * 64 + 63;      // block bound

    bf16x8 sk0 = *(const bf16x8*)&kg[0];
    bf16x8 sk1 = *(const bf16x8*)&kg[32 * 1024];
    bf16x8 sv0 = *(const bf16x8*)&vg[0];
    bf16x8 sv1 = *(const bf16x8*)&vg[32 * 1024];

    for (int j0 = 0; j0 <= jend; j0 += 64) {
        __syncthreads();  // LDS safe to overwrite
        *(bf16x8*)kw0 = sk0;
        *(bf16x8*)kw1 = sk1;
        *(bf16x8*)vw0 = sv0;
        *(bf16x8*)vw1 = sv1;
        __syncthreads();
        // async-split: issue next tile's global loads now, consume next iter
        if (j0 + 64 <= jend) {
            sk0 = *(const bf16x8*)&kg[(size_t)(j0 + 64) * 1024];
            sk1 = *(const bf16x8*)&kg[(size_t)(j0 + 64) * 1024 + 32 * 1024];
            sv0 = *(const bf16x8*)&vg[j0 + 64];
            sv1 = *(const bf16x8*)&vg[32 * 1024 + j0 + 64];
        }

        if (j0 <= jmaxw) {
            // QK^T: s[kt] covers keys j0+kt*16+lr, q rows qbase+4lh+r
            f32x4 s[4] = {{0,0,0,0},{0,0,0,0},{0,0,0,0},{0,0,0,0}};
#pragma unroll
            for (int kt = 0; kt < 4; ++kt) {
                const int row = kt * 16 + lr;
                const int rswz = ((row & 7) << 4);
#pragma unroll
                for (int ks = 0; ks < 2; ++ks) {
                    bf16x8 kf = *(const bf16x8*)(kbase + row * 128 + ((ks * 64 + lh * 16) ^ rswz));
                    s[kt] = MFMA16(qf[ks], kf, s[kt]);
                }
            }
            if (j0 + 63 > qbase) {  // diagonal tile (wave-uniform): mask
#pragma unroll
                for (int kt = 0; kt < 4; ++kt)
#pragma unroll
                    for (int r = 0; r < 4; ++r)
                        s[kt][r] = ((j0 + kt * 16 + lr) <= (qbase + lh * 4 + r)) ? s[kt][r] : -1e9f;
            }
            // online softmax: row q = qbase+4lh+r lives in 16-lane groups
#pragma unroll
            for (int r = 0; r < 4; ++r) {
                float pm = fmaxf(fmaxf(s[0][r], s[1][r]), fmaxf(s[2][r], s[3][r]));
                pm = fmaxf(pm, __shfl_xor(pm, 1, 16));
                pm = fmaxf(pm, __shfl_xor(pm, 2, 16));
                pm = fmaxf(pm, __shfl_xor(pm, 4, 16));
                pm = fmaxf(pm, __shfl_xor(pm, 8, 16));
                const float mn = fmaxf(m[r], pm);
                const float corr = __expf(m[r] - mn);
                m[r] = mn;
                float p0 = __expf(s[0][r] - mn);
                float p1 = __expf(s[1][r] - mn);
                float p2 = __expf(s[2][r] - mn);
                float p3 = __expf(s[3][r] - mn);
                s[0][r] = p0; s[1][r] = p1; s[2][r] = p2; s[3][r] = p3;
                float ps = (p0 + p1) + (p2 + p3);
                ps += __shfl_xor(ps, 1, 16);
                ps += __shfl_xor(ps, 2, 16);
                ps += __shfl_xor(ps, 4, 16);
                ps += __shfl_xor(ps, 8, 16);
                ls[r] = ls[r] * corr + ps;
                oacc[0][r] *= corr; oacc[1][r] *= corr;
                oacc[2][r] *= corr; oacc[3][r] *= corr;
            }
            // P -> wave-private LDS (swizzled), then A-frag reads
            char* const pb = (char*)p_lds[w];
#pragma unroll
            for (int r = 0; r < 4; ++r) {
                const int qrow = lh * 4 + r;
                const int qswz = ((qrow & 7) << 4);
#pragma unroll
                for (int kt = 0; kt < 4; ++kt)
                    *(ushort_t*)(pb + qrow * 128 + ((kt * 32 + lr * 2) ^ qswz)) = f2bf(s[kt][r]);
            }
            const int pswz = ((lr & 7) << 4);
            bf16x8 pa0 = *(const bf16x8*)(pb + lr * 128 + ((lh * 16) ^ pswz));
            bf16x8 pa1 = *(const bf16x8*)(pb + lr * 128 + ((64 + lh * 16) ^ pswz));
#pragma unroll
            for (int dt = 0; dt < 4; ++dt) {
                const int vrow = dt * 16 + lr;
                const int vswz = ((vrow & 7) << 4);
                bf16x8 vf0 = *(const bf16x8*)(vbase + vrow * 128 + ((lh * 16) ^ vswz));
                oacc[dt] = MFMA16(pa0, vf0, oacc[dt]);
                bf16x8 vf1 = *(const bf16x8*)(vbase + vrow * 128 + ((64 + lh * 16) ^ vswz));
                oacc[dt] = MFMA16(pa1, vf1, oacc[dt]);
            }
        }
    }

    float inv[4];
#pragma unroll
    for (int r = 0; r < 4; ++r) inv[r] = 1.f / ls[r];
#pragma unroll
    for (int dt = 0; dt < 4; ++dt)
#pragma unroll
        for (int r = 0; r < 4; ++r) {
            const int row = qbase + lh * 4 + r;
            o[headoff + (size_t)row * 1024 + dt * 16 + lr] = f2bf(oacc[dt][r] * inv[r]);
        }
}

// ---------------------------------------------------------------------------
// fused residual + LayerNorm on bf16 residual stream: y = LN(t + xr).
// LAST=0: xr <- bf16(y).  LAST=1: out (f32, d_out) <- y.
// ---------------------------------------------------------------------------
template <int LAST>
__global__ __launch_bounds__(256) void add_ln(const ushort_t* __restrict__ t,
                                              ushort_t* __restrict__ xr,
                                              const float* __restrict__ g,
                                              const float* __restrict__ bb,
                                              float* __restrict__ out) {
    const int row = blockIdx.x, tid = threadIdx.x;
    const int lane = tid & 63, w = tid >> 6;
    const size_t base = (size_t)row * 1024;
    ushort4 tv = ((const ushort4*)(t + base))[tid];
    ushort4 xv = ((const ushort4*)(xr + base))[tid];
    float v0 = bf2f(tv.x) + bf2f(xv.x), v1 = bf2f(tv.y) + bf2f(xv.y);
    float v2 = bf2f(tv.z) + bf2f(xv.z), v3 = bf2f(tv.w) + bf2f(xv.w);
    float s = v0 + v1 + v2 + v3;
    float sq = v0 * v0 + v1 * v1 + v2 * v2 + v3 * v3;
#pragma unroll
    for (int off = 32; off >= 1; off >>= 1) {
        s += __shfl_xor(s, off);
        sq += __shfl_xor(sq, off);
    }
    __shared__ float red[8];
    if (lane == 0) { red[w] = s; red[4 + w] = sq; }
    __syncthreads();
    s = red[0] + red[1] + red[2] + red[3];
    sq = red[4] + red[5] + red[6] + red[7];
    const float mu = s * (1.f / 1024.f);
    const float var = sq * (1.f / 1024.f) - mu * mu;
    const float rs = rsqrtf(var + 1e-6f);
    float4 gv = ((const float4*)g)[tid];
    float4 bv = ((const float4*)bb)[tid];
    float y0 = (v0 - mu) * rs * gv.x + bv.x;
    float y1 = (v1 - mu) * rs * gv.y + bv.y;
    float y2 = (v2 - mu) * rs * gv.z + bv.z;
    float y3 = (v3 - mu) * rs * gv.w + bv.w;
    if (LAST) {
        float4 yo; yo.x = y0; yo.y = y1; yo.z = y2; yo.w = y3;
        ((float4*)(out + base))[tid] = yo;
    } else {
        ushort4 hh;
        hh.x = f2bf(y0); hh.y = f2bf(y1); hh.z = f2bf(y2); hh.w = f2bf(y3);
        ((ushort4*)(xr + base))[tid] = hh;
    }
}

// ---------------------------------------------------------------------------
extern "C" void kernel_launch(void* const* d_in, const int* in_sizes, int n_in,
                              void* d_out, int out_size, void* d_ws, size_t ws_size,
                              hipStream_t stream) {
    (void)in_sizes; (void)n_in; (void)out_size; (void)ws_size;
    const int B = 8, S = 1024, D = 1024, DFF = 4096, L = 2;
    const int M = B * S;  // 8192

    const float* x_in = (const float*)d_in[0];
    const float* Wq = (const float*)d_in[2];
    const float* bq = (const float*)d_in[3];
    const float* Wk = (const float*)d_in[4];
    const float* bk = (const float*)d_in[5];
    const float* Wv = (const float*)d_in[6];
    const float* bv = (const float*)d_in[7];
    const float* Wo = (const float*)d_in[8];
    const float* bo = (const float*)d_in[9];
    const float* W1 = (const float*)d_in[10];
    const float* b1 = (const float*)d_in[11];
    const float* W2 = (const float*)d_in[12];
    const float* b2 = (const float*)d_in[13];
    const float* ln1g = (const float*)d_in[14];
    const float* ln1b = (const float*)d_in[15];
    const float* ln2g = (const float*)d_in[16];
    const float* ln2b = (const float*)d_in[17];

    float* out = (float*)d_out;  // final f32 output only
    char* ws = (char*)d_ws;
    const size_t MB = 1024 * 1024;
    ushort_t* wqkvT = (ushort_t*)(ws + 0 * MB);   // 12MB (2 layers x 3072x1024)
    ushort_t* woT = (ushort_t*)(ws + 12 * MB);    // 4MB
    ushort_t* w1T = (ushort_t*)(ws + 16 * MB);    // 16MB
    ushort_t* w2T = (ushort_t*)(ws + 32 * MB);    // 16MB
    ushort_t* xr  = (ushort_t*)(ws + 48 * MB);    // 16MB bf16 residual stream
    ushort_t* qb  = (ushort_t*)(ws + 64 * MB);    // 16MB
    ushort_t* kb  = (ushort_t*)(ws + 80 * MB);    // 16MB
    ushort_t* vtb = (ushort_t*)(ws + 96 * MB);    // 16MB  (B,H,DH,S)
    ushort_t* ob  = (ushort_t*)(ws + 112 * MB);   // 16MB
    ushort_t* hb  = (ushort_t*)(ws + 64 * MB);    // 64MB, reuses q/k/vt/o region
    ushort_t* tb  = (ushort_t*)(ws + 128 * MB);   // 16MB bf16 pre-LN summand

    init_x<<<M * D / 4 / 256, 256, 0, stream>>>(x_in, xr, M * D / 4);
    transpose_all<<<dim3(12288, L), dim3(32, 8), 0, stream>>>(
        Wq, Wk, Wv, Wo, W1, W2, wqkvT, woT, w1T, w2T);

    for (int l = 0; l < L; ++l) {
        const size_t wOff = (size_t)l * D * D;
        const size_t bOff = (size_t)l * D;
        // QKV: M=8192, N=3072, K=1024; 128x256 tiles -> 64x12 = 768 blocks (3/CU)
        gemm8p<128, 2, 0><<<dim3(768), 512, 0, stream>>>(
            xr, wqkvT + (size_t)l * 3 * D * D, nullptr, nullptr, M, 3 * D, D, 12,
            qb, kb, vtb, bq + bOff, bk + bOff, bv + bOff);
        attn_kernel<<<dim3(B * 16, S / 64), 256, 0, stream>>>(qb, kb, vtb, ob);
        // Wo: N=1024; 128x256 tiles -> 64x4 = 256 blocks; bf16 out -> tb
        gemm8p<128, 1, 0><<<dim3(256), 512, 0, stream>>>(
            ob, woT + wOff, bo + bOff, tb, M, D, D, 4,
            nullptr, nullptr, nullptr, nullptr, nullptr, nullptr);
        add_ln<0><<<M, 256, 0, stream>>>(tb, xr, ln1g + bOff, ln1b + bOff, nullptr);
        // FFN1: N=4096; 256x256 -> 32x16 = 512 blocks (2 rounds)
        gemm8p<256, 1, 1><<<dim3(512), 512, 0, stream>>>(
            xr, w1T + (size_t)l * D * DFF, b1 + (size_t)l * DFF, hb, M, DFF, D, 16,
            nullptr, nullptr, nullptr, nullptr, nullptr, nullptr);
        // FFN2: N=1024, K=4096; 128x256 -> 256 blocks; bf16 out -> tb
        gemm8p<128, 1, 0><<<dim3(256), 512, 0, stream>>>(
            hb, w2T + (size_t)l * DFF * D, b2 + bOff, tb, M, D, DFF, 4,
            nullptr, nullptr, nullptr, nullptr, nullptr, nullptr);
        if (l == L - 1)
            add_ln<1><<<M, 256, 0, stream>>>(tb, xr, ln2g + bOff, ln2b + bOff, out);
        else
            add_ln<0><<<M, 256, 0, stream>>>(tb, xr, ln2g + bOff, ln2b + bOff, nullptr);
    }
}